// Round 1
// baseline (1148.684 us; speedup 1.0000x reference)
//
#include <hip/hip_runtime.h>

// Problem constants (from reference): N_NODES=100000, N_EDGES=50000, NNZ=1600000
// dims 128 -> 128 -> 16. All fp32; indices int32 (JAX default x64 disabled).

#define N_EDGES_C 50000
#define F1 128
#define F2 16

// ---------------- CSR build ----------------

__global__ __launch_bounds__(256) void hist_kernel(
    const int* __restrict__ node_idx, const int* __restrict__ edge_idx,
    int* __restrict__ ncnt, int* __restrict__ ecnt, int nnz) {
  int i = blockIdx.x * 256 + threadIdx.x;
  if (i >= nnz) return;
  atomicAdd(&ecnt[edge_idx[i]], 1);
  atomicAdd(&ncnt[node_idx[i]], 1);
}

// single-block chunked exclusive scan; blockDim must be 1024
__global__ __launch_bounds__(1024) void scan_excl_kernel(
    const int* __restrict__ cnt, int* __restrict__ off, int n) {
  __shared__ int sums[1024];
  const int t = threadIdx.x;
  const int C = (n + 1023) >> 10;
  int beg = t * C;
  int end = beg + C; if (end > n) end = n;
  int s = 0;
  for (int i = beg; i < end; ++i) s += cnt[i];
  sums[t] = s;
  __syncthreads();
  // Hillis-Steele inclusive scan over 1024
  for (int d = 1; d < 1024; d <<= 1) {
    int v = (t >= d) ? sums[t - d] : 0;
    __syncthreads();
    sums[t] += v;
    __syncthreads();
  }
  int p = (t > 0) ? sums[t - 1] : 0;
  for (int i = beg; i < end; ++i) { off[i] = p; p += cnt[i]; }
  if (t == 1023) off[n] = sums[1023];
}

__global__ __launch_bounds__(256) void scatter_kernel(
    const int* __restrict__ node_idx, const int* __restrict__ edge_idx,
    const int* __restrict__ noff, const int* __restrict__ eoff,
    int* __restrict__ ncur, int* __restrict__ ecur,
    int* __restrict__ node_nbr, int* __restrict__ edge_nbr, int nnz) {
  int i = blockIdx.x * 256 + threadIdx.x;
  if (i >= nnz) return;
  int e = edge_idx[i];
  int n = node_idx[i];
  int pe = eoff[e] + atomicAdd(&ecur[e], 1);
  edge_nbr[pe] = n;   // for each edge: list of incident nodes (with multiplicity)
  int pn = noff[n] + atomicAdd(&ncur[n], 1);
  node_nbr[pn] = e;   // for each node: list of incident edges
}

// ---------------- GEMM1: xw[M x 128] = x[M x 128] @ W[128 x 128] ----------------
// Block computes 128x128 tile, 256 threads, 8x8 accum per thread, K-tiles of 32.

__global__ __launch_bounds__(256) void gemm1_kernel(
    const float* __restrict__ A, const float* __restrict__ B,
    float* __restrict__ Cmat, int M) {
  __shared__ float xs[128][36];   // [row][k-in-tile], +4 pad keeps f4 align & banks clean
  __shared__ float wsh[32][128];  // [k-in-tile][col]

  const int t = threadIdx.x;
  const int tx = t & 15;
  const int ty = t >> 4;
  const int bm = blockIdx.x * 128;

  float acc[8][8];
#pragma unroll
  for (int i = 0; i < 8; ++i)
#pragma unroll
    for (int j = 0; j < 8; ++j) acc[i][j] = 0.f;

  for (int kt = 0; kt < 4; ++kt) {
    // load A tile: 128 rows x 32 cols = 1024 float4
#pragma unroll
    for (int i = 0; i < 4; ++i) {
      int lin = i * 256 + t;
      int row = lin >> 3;
      int c4 = lin & 7;
      int grow = bm + row;
      float4 v = make_float4(0.f, 0.f, 0.f, 0.f);
      if (grow < M) v = *(const float4*)(A + (size_t)grow * 128 + kt * 32 + c4 * 4);
      *(float4*)&xs[row][c4 * 4] = v;
    }
    // load B tile: 32 rows x 128 cols = 1024 float4
#pragma unroll
    for (int i = 0; i < 4; ++i) {
      int lin = i * 256 + t;
      int k = lin >> 5;
      int c4 = lin & 31;
      *(float4*)&wsh[k][c4 * 4] = *(const float4*)(B + (size_t)(kt * 32 + k) * 128 + c4 * 4);
    }
    __syncthreads();

#pragma unroll 4
    for (int k = 0; k < 32; ++k) {
      float a[8], b[8];
#pragma unroll
      for (int j = 0; j < 4; ++j) {
        a[j]     = xs[ty * 4 + j][k];
        a[4 + j] = xs[ty * 4 + 64 + j][k];
      }
      float4 b0 = *(const float4*)&wsh[k][tx * 4];
      float4 b1 = *(const float4*)&wsh[k][tx * 4 + 64];
      b[0] = b0.x; b[1] = b0.y; b[2] = b0.z; b[3] = b0.w;
      b[4] = b1.x; b[5] = b1.y; b[6] = b1.z; b[7] = b1.w;
#pragma unroll
      for (int i = 0; i < 8; ++i)
#pragma unroll
        for (int j = 0; j < 8; ++j) acc[i][j] = fmaf(a[i], b[j], acc[i][j]);
    }
    __syncthreads();
  }

  // store
#pragma unroll
  for (int i = 0; i < 8; ++i) {
    int row = (i < 4) ? (ty * 4 + i) : (ty * 4 + 64 + (i - 4));
    int grow = bm + row;
    if (grow < M) {
      float4 v0 = make_float4(acc[i][0], acc[i][1], acc[i][2], acc[i][3]);
      float4 v1 = make_float4(acc[i][4], acc[i][5], acc[i][6], acc[i][7]);
      *(float4*)(Cmat + (size_t)grow * 128 + tx * 4) = v0;
      *(float4*)(Cmat + (size_t)grow * 128 + tx * 4 + 64) = v1;
    }
  }
}

// ---------------- Segment aggregation, F=128 (one wave per segment) ----------------

__global__ __launch_bounds__(256) void edge_agg128_kernel(
    const float* __restrict__ feat, const int* __restrict__ nbr,
    const int* __restrict__ off, float* __restrict__ outf, int nseg) {
  int w = (blockIdx.x * 256 + threadIdx.x) >> 6;
  int lane = threadIdx.x & 63;
  if (w >= nseg) return;
  int beg = off[w], end = off[w + 1];
  float ax = 0.f, ay = 0.f;
  for (int j = beg; j < end; ++j) {
    int n = nbr[j];
    float2 v = *(const float2*)(feat + (size_t)n * 128 + lane * 2);
    ax += v.x; ay += v.y;
  }
  float inv = (end > beg) ? 1.f / (float)(end - beg) : 0.f;
  float2 r; r.x = ax * inv; r.y = ay * inv;
  *(float2*)(outf + (size_t)w * 128 + lane * 2) = r;
}

__global__ __launch_bounds__(256) void node_agg128_kernel(
    const float* __restrict__ feat, const int* __restrict__ nbr,
    const int* __restrict__ off, const float* __restrict__ bias,
    float* __restrict__ outf, int nseg) {
  int w = (blockIdx.x * 256 + threadIdx.x) >> 6;
  int lane = threadIdx.x & 63;
  if (w >= nseg) return;
  int beg = off[w], end = off[w + 1];
  float ax = 0.f, ay = 0.f;
  for (int j = beg; j < end; ++j) {
    int e = nbr[j];
    float2 v = *(const float2*)(feat + (size_t)e * 128 + lane * 2);
    ax += v.x; ay += v.y;
  }
  float inv = (end > beg) ? 1.f / (float)(end - beg) : 0.f;
  float2 b = *(const float2*)(bias + lane * 2);
  float2 r;
  r.x = fmaxf(ax * inv + b.x, 0.f);  // + b1, ReLU
  r.y = fmaxf(ay * inv + b.y, 0.f);
  *(float2*)(outf + (size_t)w * 128 + lane * 2) = r;
}

// ---------------- GEMM2: hw2[M x 16] = h[M x 128] @ W2[128 x 16] ----------------
// 2 rows per thread; W2 staged in LDS (8 KB), broadcast reads.

__global__ __launch_bounds__(256) void gemm2_kernel(
    const float* __restrict__ H, const float* __restrict__ W2,
    float* __restrict__ O, int M) {
  __shared__ float ws2[128 * 16];
  const int t = threadIdx.x;
#pragma unroll
  for (int i = 0; i < 8; ++i) ws2[i * 256 + t] = W2[i * 256 + t];
  __syncthreads();

  int r0 = blockIdx.x * 512 + t;
  int r1 = r0 + 256;
  bool v0 = r0 < M, v1 = r1 < M;
  const float4* h0 = (const float4*)(H + (size_t)r0 * 128);
  const float4* h1 = (const float4*)(H + (size_t)r1 * 128);

  float4 acc0[4], acc1[4];
#pragma unroll
  for (int q = 0; q < 4; ++q) {
    acc0[q] = make_float4(0.f, 0.f, 0.f, 0.f);
    acc1[q] = make_float4(0.f, 0.f, 0.f, 0.f);
  }

  for (int k4 = 0; k4 < 32; ++k4) {
    float4 a0 = v0 ? h0[k4] : make_float4(0.f, 0.f, 0.f, 0.f);
    float4 a1 = v1 ? h1[k4] : make_float4(0.f, 0.f, 0.f, 0.f);
    const float a0s[4] = {a0.x, a0.y, a0.z, a0.w};
    const float a1s[4] = {a1.x, a1.y, a1.z, a1.w};
#pragma unroll
    for (int j = 0; j < 4; ++j) {
      int k = k4 * 4 + j;
#pragma unroll
      for (int q = 0; q < 4; ++q) {
        float4 b = *(const float4*)&ws2[k * 16 + q * 4];
        acc0[q].x = fmaf(a0s[j], b.x, acc0[q].x);
        acc0[q].y = fmaf(a0s[j], b.y, acc0[q].y);
        acc0[q].z = fmaf(a0s[j], b.z, acc0[q].z);
        acc0[q].w = fmaf(a0s[j], b.w, acc0[q].w);
        acc1[q].x = fmaf(a1s[j], b.x, acc1[q].x);
        acc1[q].y = fmaf(a1s[j], b.y, acc1[q].y);
        acc1[q].z = fmaf(a1s[j], b.z, acc1[q].z);
        acc1[q].w = fmaf(a1s[j], b.w, acc1[q].w);
      }
    }
  }
  if (v0) {
#pragma unroll
    for (int q = 0; q < 4; ++q) *(float4*)(O + (size_t)r0 * 16 + q * 4) = acc0[q];
  }
  if (v1) {
#pragma unroll
    for (int q = 0; q < 4; ++q) *(float4*)(O + (size_t)r1 * 16 + q * 4) = acc1[q];
  }
}

// ---------------- Segment aggregation, F=16 (16 lanes per segment) ----------------

__global__ __launch_bounds__(256) void edge_agg16_kernel(
    const float* __restrict__ feat, const int* __restrict__ nbr,
    const int* __restrict__ off, float* __restrict__ outf, int nseg) {
  int gid = blockIdx.x * 256 + threadIdx.x;
  int seg = gid >> 4;
  int c = gid & 15;
  if (seg >= nseg) return;
  int beg = off[seg], end = off[seg + 1];
  float acc = 0.f;
  for (int j = beg; j < end; ++j) acc += feat[(size_t)nbr[j] * 16 + c];
  float inv = (end > beg) ? 1.f / (float)(end - beg) : 0.f;
  outf[(size_t)seg * 16 + c] = acc * inv;
}

__global__ __launch_bounds__(256) void node_agg16_kernel(
    const float* __restrict__ feat, const int* __restrict__ nbr,
    const int* __restrict__ off, const float* __restrict__ bias,
    float* __restrict__ outf, int nseg) {
  int gid = blockIdx.x * 256 + threadIdx.x;
  int seg = gid >> 4;
  int c = gid & 15;
  if (seg >= nseg) return;
  int beg = off[seg], end = off[seg + 1];
  float acc = 0.f;
  for (int j = beg; j < end; ++j) acc += feat[(size_t)nbr[j] * 16 + c];
  float inv = (end > beg) ? 1.f / (float)(end - beg) : 0.f;
  outf[(size_t)seg * 16 + c] = acc * inv + bias[c];
}

// ---------------- launch ----------------

extern "C" void kernel_launch(void* const* d_in, const int* in_sizes, int n_in,
                              void* d_out, int out_size, void* d_ws, size_t ws_size,
                              hipStream_t stream) {
  const float* x        = (const float*)d_in[0];
  const int*   node_idx = (const int*)d_in[1];
  const int*   edge_idx = (const int*)d_in[2];
  // d_in[3] = num_edges scalar on device; constant 50000 per reference
  const float* W1 = (const float*)d_in[4];
  const float* b1 = (const float*)d_in[5];
  const float* W2 = (const float*)d_in[6];
  const float* b2 = (const float*)d_in[7];
  float* out = (float*)d_out;

  const int n_nodes = in_sizes[0] / F1;  // 100000
  const int nnz     = in_sizes[1];       // 1600000
  const int n_edges = N_EDGES_C;         // 50000

  char* ws = (char*)d_ws;
  // layout (bytes)
  float* feat   = (float*)(ws + 0);           // 51,200,000 : xw, later reused as h
  float* efeat  = (float*)(ws + 51200000);    // 25,600,000 : e_feat (L1), e_feat2 (L2)
  float* hw2    = (float*)(ws + 76800000);    //  6,400,000
  int*   enbr   = (int*)(ws + 83200000);      //  6,400,000
  int*   nnbr   = (int*)(ws + 89600000);      //  6,400,000
  int*   cntblk = (int*)(ws + 96000000);      //  1,200,000 : ecnt|ncnt|ecur|ncur
  int*   ecnt   = cntblk;
  int*   ncnt   = cntblk + n_edges;
  int*   ecur   = cntblk + n_edges + n_nodes;
  int*   ncur   = cntblk + 2 * n_edges + n_nodes;
  int*   eoff   = (int*)(ws + 97200128);      // 50001 ints
  int*   noff   = (int*)(ws + 97400576);      // 100001 ints

  // ws is poisoned 0xAA before every call: zero the counters we accumulate into
  hipMemsetAsync(cntblk, 0, (size_t)(2 * (n_edges + n_nodes)) * sizeof(int), stream);

  const int nnzBlocks = (nnz + 255) / 256;
  hist_kernel<<<nnzBlocks, 256, 0, stream>>>(node_idx, edge_idx, ncnt, ecnt, nnz);
  scan_excl_kernel<<<1, 1024, 0, stream>>>(ecnt, eoff, n_edges);
  scan_excl_kernel<<<1, 1024, 0, stream>>>(ncnt, noff, n_nodes);
  scatter_kernel<<<nnzBlocks, 256, 0, stream>>>(node_idx, edge_idx, noff, eoff,
                                                ncur, ecur, nnbr, enbr, nnz);

  // layer 1
  gemm1_kernel<<<(n_nodes + 127) / 128, 256, 0, stream>>>(x, W1, feat, n_nodes);
  edge_agg128_kernel<<<(n_edges * 64 + 255) / 256, 256, 0, stream>>>(feat, enbr, eoff, efeat, n_edges);
  node_agg128_kernel<<<(n_nodes * 64 + 255) / 256, 256, 0, stream>>>(efeat, nnbr, noff, b1, feat, n_nodes);

  // layer 2
  gemm2_kernel<<<(n_nodes + 511) / 512, 256, 0, stream>>>(feat, W2, hw2, n_nodes);
  edge_agg16_kernel<<<(n_edges * 16 + 255) / 256, 256, 0, stream>>>(hw2, enbr, eoff, efeat, n_edges);
  node_agg16_kernel<<<(n_nodes * 16 + 255) / 256, 256, 0, stream>>>(efeat, nnbr, noff, b2, out, n_nodes);
}

// Round 3
// 1128.619 us; speedup vs baseline: 1.0178x; 1.0178x over previous
//
#include <hip/hip_runtime.h>

// Problem constants: N_NODES=100000, N_EDGES=50000, NNZ=1600000, dims 128->128->16, fp32.

#define N_EDGES_C 50000
#define F1 128
#define F2 16
#define NNZ_CHUNK 2048
#define EBIN_SHIFT 7              // 128 edges per bin
#define NBIN_SHIFT 8              // 256 nodes per bin
#define EBINS 391                 // ceil(50000/128)
#define NBINS 391                 // ceil(100000/256)

// ---------------- CSR build ----------------

__global__ __launch_bounds__(256) void hist_kernel(
    const int* __restrict__ node_idx, const int* __restrict__ edge_idx,
    int* __restrict__ ncnt, int* __restrict__ ecnt, int nnz) {
  int i = blockIdx.x * 256 + threadIdx.x;
  if (i >= nnz) return;
  atomicAdd(&ecnt[edge_idx[i]], 1);
  atomicAdd(&ncnt[node_idx[i]], 1);
}

// single-block chunked exclusive scan; blockDim must be 1024
__global__ __launch_bounds__(1024) void scan_excl_kernel(
    const int* __restrict__ cnt, int* __restrict__ off, int n) {
  __shared__ int sums[1024];
  const int t = threadIdx.x;
  const int C = (n + 1023) >> 10;
  int beg = t * C;
  int end = beg + C; if (end > n) end = n;
  int s = 0;
  for (int i = beg; i < end; ++i) s += cnt[i];
  sums[t] = s;
  __syncthreads();
  for (int d = 1; d < 1024; d <<= 1) {
    int v = (t >= d) ? sums[t - d] : 0;
    __syncthreads();
    sums[t] += v;
    __syncthreads();
  }
  int p = (t > 0) ? sums[t - 1] : 0;
  for (int i = beg; i < end; ++i) { off[i] = p; p += cnt[i]; }
  if (t == 1023) off[n] = sums[1023];
}

// Pass 1: XCD-grouped binning partition. group = blockIdx&7 (round-robin lands
// consecutive blocks on distinct XCDs, so each bin-group's pair writes are
// assembled into full lines inside one XCD's L2). Correctness does not depend
// on the XCD mapping -- coverage is deterministic (each chunk visited by all 8
// groups).
__global__ __launch_bounds__(256) void partition_kernel(
    const int* __restrict__ node_idx, const int* __restrict__ edge_idx,
    const int* __restrict__ eoff, const int* __restrict__ noff,
    int* __restrict__ ebincur, int* __restrict__ nbincur,
    int2* __restrict__ epairs, int2* __restrict__ npairs, int nnz) {
  const int g = blockIdx.x & 7;
  const int c = blockIdx.x >> 3;
  const int base = c * NNZ_CHUNK;
  int end = base + NNZ_CHUNK; if (end > nnz) end = nnz;
  for (int i = base + threadIdx.x; i < end; i += 256) {
    int e = edge_idx[i];
    int n = node_idx[i];
    int eb = e >> EBIN_SHIFT;
    if ((eb & 7) == g) {
      int pos = eoff[eb << EBIN_SHIFT] + atomicAdd(&ebincur[eb * 16], 1);
      epairs[pos] = make_int2(e, n);
    }
    int nb = n >> NBIN_SHIFT;
    if ((nb & 7) == g) {
      int pos = noff[nb << NBIN_SHIFT] + atomicAdd(&nbincur[nb * 16], 1);
      npairs[pos] = make_int2(n, e);
    }
  }
}

// Pass 2: one block per bin; LDS rank counters; writes confined to the bin's
// small CSR window from a single block -> full-line writebacks.
__global__ __launch_bounds__(256) void bin_scatter_kernel(
    const int2* __restrict__ epairs, const int2* __restrict__ npairs,
    const int* __restrict__ eoff, const int* __restrict__ noff,
    int* __restrict__ enbr, int* __restrict__ nnbr,
    int n_edges, int n_nodes) {
  __shared__ int cnt[256];
  const int bid = blockIdx.x;
  const int t = threadIdx.x;
  if (bid < EBINS) {
    int e0 = bid << EBIN_SHIFT;
    int e1 = e0 + (1 << EBIN_SHIFT); if (e1 > n_edges) e1 = n_edges;
    if (t < 128) cnt[t] = 0;
    __syncthreads();
    int beg = eoff[e0], end = eoff[e1];
    for (int j = beg + t; j < end; j += 256) {
      int2 p = epairs[j];
      int pos = eoff[p.x] + atomicAdd(&cnt[p.x & 127], 1);
      enbr[pos] = p.y;
    }
  } else {
    int b = bid - EBINS;
    int n0 = b << NBIN_SHIFT;
    int n1 = n0 + (1 << NBIN_SHIFT); if (n1 > n_nodes) n1 = n_nodes;
    cnt[t] = 0;
    __syncthreads();
    int beg = noff[n0], end = noff[n1];
    for (int j = beg + t; j < end; j += 256) {
      int2 p = npairs[j];
      int pos = noff[p.x] + atomicAdd(&cnt[p.x & 255], 1);
      nnbr[pos] = p.y;
    }
  }
}

// ---------------- GEMM1: xw[M x 128] = x[M x 128] @ W[128 x 128] ----------------

__global__ __launch_bounds__(256) void gemm1_kernel(
    const float* __restrict__ A, const float* __restrict__ B,
    float* __restrict__ Cmat, int M) {
  __shared__ float xs[128][36];
  __shared__ float wsh[32][128];

  const int t = threadIdx.x;
  const int tx = t & 15;
  const int ty = t >> 4;
  const int bm = blockIdx.x * 128;

  float acc[8][8];
#pragma unroll
  for (int i = 0; i < 8; ++i)
#pragma unroll
    for (int j = 0; j < 8; ++j) acc[i][j] = 0.f;

  for (int kt = 0; kt < 4; ++kt) {
#pragma unroll
    for (int i = 0; i < 4; ++i) {
      int lin = i * 256 + t;
      int row = lin >> 3;
      int c4 = lin & 7;
      int grow = bm + row;
      float4 v = make_float4(0.f, 0.f, 0.f, 0.f);
      if (grow < M) v = *(const float4*)(A + (size_t)grow * 128 + kt * 32 + c4 * 4);
      *(float4*)&xs[row][c4 * 4] = v;
    }
#pragma unroll
    for (int i = 0; i < 4; ++i) {
      int lin = i * 256 + t;
      int k = lin >> 5;
      int c4 = lin & 31;
      *(float4*)&wsh[k][c4 * 4] = *(const float4*)(B + (size_t)(kt * 32 + k) * 128 + c4 * 4);
    }
    __syncthreads();

#pragma unroll 4
    for (int k = 0; k < 32; ++k) {
      float a[8], b[8];
#pragma unroll
      for (int j = 0; j < 4; ++j) {
        a[j]     = xs[ty * 4 + j][k];
        a[4 + j] = xs[ty * 4 + 64 + j][k];
      }
      float4 b0 = *(const float4*)&wsh[k][tx * 4];
      float4 b1 = *(const float4*)&wsh[k][tx * 4 + 64];
      b[0] = b0.x; b[1] = b0.y; b[2] = b0.z; b[3] = b0.w;
      b[4] = b1.x; b[5] = b1.y; b[6] = b1.z; b[7] = b1.w;
#pragma unroll
      for (int i = 0; i < 8; ++i)
#pragma unroll
        for (int j = 0; j < 8; ++j) acc[i][j] = fmaf(a[i], b[j], acc[i][j]);
    }
    __syncthreads();
  }

#pragma unroll
  for (int i = 0; i < 8; ++i) {
    int row = (i < 4) ? (ty * 4 + i) : (ty * 4 + 64 + (i - 4));
    int grow = bm + row;
    if (grow < M) {
      float4 v0 = make_float4(acc[i][0], acc[i][1], acc[i][2], acc[i][3]);
      float4 v1 = make_float4(acc[i][4], acc[i][5], acc[i][6], acc[i][7]);
      *(float4*)(Cmat + (size_t)grow * 128 + tx * 4) = v0;
      *(float4*)(Cmat + (size_t)grow * 128 + tx * 4 + 64) = v1;
    }
  }
}

// ---------------- Segment aggregation, F=128 (one wave per segment) ----------------

__global__ __launch_bounds__(256) void edge_agg128_kernel(
    const float* __restrict__ feat, const int* __restrict__ nbr,
    const int* __restrict__ off, float* __restrict__ outf, int nseg) {
  int w = (blockIdx.x * 256 + threadIdx.x) >> 6;
  int lane = threadIdx.x & 63;
  if (w >= nseg) return;
  int beg = off[w], end = off[w + 1];
  float ax = 0.f, ay = 0.f;
  for (int j = beg; j < end; ++j) {
    int n = nbr[j];
    float2 v = *(const float2*)(feat + (size_t)n * 128 + lane * 2);
    ax += v.x; ay += v.y;
  }
  float inv = (end > beg) ? 1.f / (float)(end - beg) : 0.f;
  float2 r; r.x = ax * inv; r.y = ay * inv;
  *(float2*)(outf + (size_t)w * 128 + lane * 2) = r;
}

__global__ __launch_bounds__(256) void node_agg128_kernel(
    const float* __restrict__ feat, const int* __restrict__ nbr,
    const int* __restrict__ off, const float* __restrict__ bias,
    float* __restrict__ outf, int nseg) {
  int w = (blockIdx.x * 256 + threadIdx.x) >> 6;
  int lane = threadIdx.x & 63;
  if (w >= nseg) return;
  int beg = off[w], end = off[w + 1];
  float ax = 0.f, ay = 0.f;
  for (int j = beg; j < end; ++j) {
    int e = nbr[j];
    float2 v = *(const float2*)(feat + (size_t)e * 128 + lane * 2);
    ax += v.x; ay += v.y;
  }
  float inv = (end > beg) ? 1.f / (float)(end - beg) : 0.f;
  float2 b = *(const float2*)(bias + lane * 2);
  float2 r;
  r.x = fmaxf(ax * inv + b.x, 0.f);
  r.y = fmaxf(ay * inv + b.y, 0.f);
  *(float2*)(outf + (size_t)w * 128 + lane * 2) = r;
}

// ---------------- GEMM2: hw2[M x 16] = h[M x 128] @ W2[128 x 16] ----------------

__global__ __launch_bounds__(256) void gemm2_kernel(
    const float* __restrict__ H, const float* __restrict__ W2,
    float* __restrict__ O, int M) {
  __shared__ float ws2[128 * 16];
  const int t = threadIdx.x;
#pragma unroll
  for (int i = 0; i < 8; ++i) ws2[i * 256 + t] = W2[i * 256 + t];
  __syncthreads();

  int r0 = blockIdx.x * 512 + t;
  int r1 = r0 + 256;
  bool v0 = r0 < M, v1 = r1 < M;
  const float4* h0 = (const float4*)(H + (size_t)r0 * 128);
  const float4* h1 = (const float4*)(H + (size_t)r1 * 128);

  float4 acc0[4], acc1[4];
#pragma unroll
  for (int q = 0; q < 4; ++q) {
    acc0[q] = make_float4(0.f, 0.f, 0.f, 0.f);
    acc1[q] = make_float4(0.f, 0.f, 0.f, 0.f);
  }

  for (int k4 = 0; k4 < 32; ++k4) {
    float4 a0 = v0 ? h0[k4] : make_float4(0.f, 0.f, 0.f, 0.f);
    float4 a1 = v1 ? h1[k4] : make_float4(0.f, 0.f, 0.f, 0.f);
    const float a0s[4] = {a0.x, a0.y, a0.z, a0.w};
    const float a1s[4] = {a1.x, a1.y, a1.z, a1.w};
#pragma unroll
    for (int j = 0; j < 4; ++j) {
      int k = k4 * 4 + j;
#pragma unroll
      for (int q = 0; q < 4; ++q) {
        float4 b = *(const float4*)&ws2[k * 16 + q * 4];
        acc0[q].x = fmaf(a0s[j], b.x, acc0[q].x);
        acc0[q].y = fmaf(a0s[j], b.y, acc0[q].y);
        acc0[q].z = fmaf(a0s[j], b.z, acc0[q].z);
        acc0[q].w = fmaf(a0s[j], b.w, acc0[q].w);
        acc1[q].x = fmaf(a1s[j], b.x, acc1[q].x);
        acc1[q].y = fmaf(a1s[j], b.y, acc1[q].y);
        acc1[q].z = fmaf(a1s[j], b.z, acc1[q].z);
        acc1[q].w = fmaf(a1s[j], b.w, acc1[q].w);
      }
    }
  }
  if (v0) {
#pragma unroll
    for (int q = 0; q < 4; ++q) *(float4*)(O + (size_t)r0 * 16 + q * 4) = acc0[q];
  }
  if (v1) {
#pragma unroll
    for (int q = 0; q < 4; ++q) *(float4*)(O + (size_t)r1 * 16 + q * 4) = acc1[q];
  }
}

// ---------------- Segment aggregation, F=16 ----------------

__global__ __launch_bounds__(256) void edge_agg16_kernel(
    const float* __restrict__ feat, const int* __restrict__ nbr,
    const int* __restrict__ off, float* __restrict__ outf, int nseg) {
  int gid = blockIdx.x * 256 + threadIdx.x;
  int seg = gid >> 4;
  int c = gid & 15;
  if (seg >= nseg) return;
  int beg = off[seg], end = off[seg + 1];
  float acc = 0.f;
  for (int j = beg; j < end; ++j) acc += feat[(size_t)nbr[j] * 16 + c];
  float inv = (end > beg) ? 1.f / (float)(end - beg) : 0.f;
  outf[(size_t)seg * 16 + c] = acc * inv;
}

__global__ __launch_bounds__(256) void node_agg16_kernel(
    const float* __restrict__ feat, const int* __restrict__ nbr,
    const int* __restrict__ off, const float* __restrict__ bias,
    float* __restrict__ outf, int nseg) {
  int gid = blockIdx.x * 256 + threadIdx.x;
  int seg = gid >> 4;
  int c = gid & 15;
  if (seg >= nseg) return;
  int beg = off[seg], end = off[seg + 1];
  float acc = 0.f;
  for (int j = beg; j < end; ++j) acc += feat[(size_t)nbr[j] * 16 + c];
  float inv = (end > beg) ? 1.f / (float)(end - beg) : 0.f;
  outf[(size_t)seg * 16 + c] = acc * inv + bias[c];
}

// ---------------- launch ----------------

extern "C" void kernel_launch(void* const* d_in, const int* in_sizes, int n_in,
                              void* d_out, int out_size, void* d_ws, size_t ws_size,
                              hipStream_t stream) {
  const float* x        = (const float*)d_in[0];
  const int*   node_idx = (const int*)d_in[1];
  const int*   edge_idx = (const int*)d_in[2];
  const float* W1 = (const float*)d_in[4];
  const float* b1 = (const float*)d_in[5];
  const float* W2 = (const float*)d_in[6];
  const float* b2 = (const float*)d_in[7];
  float* out = (float*)d_out;

  const int n_nodes = in_sizes[0] / F1;  // 100000
  const int nnz     = in_sizes[1];       // 1600000
  const int n_edges = N_EDGES_C;         // 50000

  char* ws = (char*)d_ws;
  // layout (bytes):
  //   [0, 51.2M)        feat (xw then h)  -- transiently reused as epairs|npairs
  //   [51.2M, 76.8M)    efeat
  //   [76.8M, 83.2M)    hw2
  //   [83.2M, 89.6M)    enbr
  //   [89.6M, 96.0M)    nnbr
  //   [96.0M, ...)      counters, eoff, noff
  float* feat   = (float*)(ws + 0);
  int2*  epairs = (int2*)(ws + 0);            // 12,800,000 (transient, pre-gemm1)
  int2*  npairs = (int2*)(ws + 12800000);     // 12,800,000 (transient, pre-gemm1)
  float* efeat  = (float*)(ws + 51200000);
  float* hw2    = (float*)(ws + 76800000);
  int*   enbr   = (int*)(ws + 83200000);
  int*   nnbr   = (int*)(ws + 89600000);
  int*   cntblk = (int*)(ws + 96000000);
  int*   ecnt    = cntblk;                        // 50000
  int*   ncnt    = cntblk + 50000;                // 100000
  int*   ebincur = cntblk + 150000;               // EBINS*16 = 6256
  int*   nbincur = cntblk + 150000 + EBINS * 16;  // NBINS*16 = 6256
  const int n_cnt = 150000 + (EBINS + NBINS) * 16;
  int*   eoff   = (int*)(ws + 96700032);      // 50001 ints
  int*   noff   = (int*)(ws + 96900352);      // 100001 ints

  hipMemsetAsync(cntblk, 0, (size_t)n_cnt * sizeof(int), stream);

  const int nnzBlocks = (nnz + 255) / 256;
  hist_kernel<<<nnzBlocks, 256, 0, stream>>>(node_idx, edge_idx, ncnt, ecnt, nnz);
  scan_excl_kernel<<<1, 1024, 0, stream>>>(ecnt, eoff, n_edges);
  scan_excl_kernel<<<1, 1024, 0, stream>>>(ncnt, noff, n_nodes);

  const int nChunks = (nnz + NNZ_CHUNK - 1) / NNZ_CHUNK;
  partition_kernel<<<8 * nChunks, 256, 0, stream>>>(node_idx, edge_idx, eoff, noff,
                                                    ebincur, nbincur, epairs, npairs, nnz);
  bin_scatter_kernel<<<EBINS + NBINS, 256, 0, stream>>>(epairs, npairs, eoff, noff,
                                                        enbr, nnbr, n_edges, n_nodes);

  // layer 1
  gemm1_kernel<<<(n_nodes + 127) / 128, 256, 0, stream>>>(x, W1, feat, n_nodes);
  edge_agg128_kernel<<<(n_edges * 64 + 255) / 256, 256, 0, stream>>>(feat, enbr, eoff, efeat, n_edges);
  node_agg128_kernel<<<(n_nodes * 64 + 255) / 256, 256, 0, stream>>>(efeat, nnbr, noff, b1, feat, n_nodes);

  // layer 2
  gemm2_kernel<<<(n_nodes + 511) / 512, 256, 0, stream>>>(feat, W2, hw2, n_nodes);
  edge_agg16_kernel<<<(n_edges * 16 + 255) / 256, 256, 0, stream>>>(hw2, enbr, eoff, efeat, n_edges);
  node_agg16_kernel<<<(n_nodes * 16 + 255) / 256, 256, 0, stream>>>(efeat, nnbr, noff, b2, out, n_nodes);
}

// Round 4
// 994.059 us; speedup vs baseline: 1.1555x; 1.1354x over previous
//
#include <hip/hip_runtime.h>
#include <hip/hip_fp16.h>

// Problem constants: N_NODES=100000, N_EDGES=50000, NNZ=1600000, dims 128->128->16, fp32 I/O.
// Internal message path (xw, e_feat, h) stored fp16, accumulated fp32.

#define N_EDGES_C 50000
#define F1 128
#define F2 16
#define CHUNK 16384               // elements per chunk for the counting sort
#define EBIN_SHIFT 7              // 128 edges per bin
#define NBIN_SHIFT 8              // 256 nodes per bin
#define EBINS 391                 // ceil(50000/128)
#define NBINS 391                 // ceil(100000/256)

// ---------------- CSR build: chunked counting sort ----------------

// Per-edge/node histogram (global atomics) + per-(chunk,bin) counts (LDS).
__global__ __launch_bounds__(256) void hist_chunk_kernel(
    const int* __restrict__ node_idx, const int* __restrict__ edge_idx,
    int* __restrict__ ncnt, int* __restrict__ ecnt,
    int* __restrict__ echunkcnt, int* __restrict__ nchunkcnt, int nnz) {
  __shared__ int ebc[EBINS], nbc[NBINS];
  const int t = threadIdx.x;
  for (int b = t; b < EBINS; b += 256) ebc[b] = 0;
  for (int b = t; b < NBINS; b += 256) nbc[b] = 0;
  __syncthreads();
  const int base = blockIdx.x * CHUNK;
  int end = base + CHUNK; if (end > nnz) end = nnz;
  for (int i = base + t; i < end; i += 256) {
    int e = edge_idx[i];
    int n = node_idx[i];
    atomicAdd(&ecnt[e], 1);
    atomicAdd(&ncnt[n], 1);
    atomicAdd(&ebc[e >> EBIN_SHIFT], 1);
    atomicAdd(&nbc[n >> NBIN_SHIFT], 1);
  }
  __syncthreads();
  const int nC = gridDim.x;
  for (int b = t; b < EBINS; b += 256) echunkcnt[b * nC + blockIdx.x] = ebc[b];
  for (int b = t; b < NBINS; b += 256) nchunkcnt[b * nC + blockIdx.x] = nbc[b];
}

// single-block chunked exclusive scan; blockDim must be 1024
__global__ __launch_bounds__(1024) void scan_excl_kernel(
    const int* __restrict__ cnt, int* __restrict__ off, int n) {
  __shared__ int sums[1024];
  const int t = threadIdx.x;
  const int C = (n + 1023) >> 10;
  int beg = t * C;
  int end = beg + C; if (end > n) end = n;
  int s = 0;
  for (int i = beg; i < end; ++i) s += cnt[i];
  sums[t] = s;
  __syncthreads();
  for (int d = 1; d < 1024; d <<= 1) {
    int v = (t >= d) ? sums[t - d] : 0;
    __syncthreads();
    sums[t] += v;
    __syncthreads();
  }
  int p = (t > 0) ? sums[t - 1] : 0;
  for (int i = beg; i < end; ++i) { off[i] = p; p += cnt[i]; }
  if (t == 1023) off[n] = sums[1023];
}

// Per-bin serial scan over chunks: run start offsets for each (bin, chunk).
__global__ __launch_bounds__(1024) void runoff_kernel(
    const int* __restrict__ eoff, const int* __restrict__ noff,
    const int* __restrict__ echunkcnt, const int* __restrict__ nchunkcnt,
    int* __restrict__ erunoff, int* __restrict__ nrunoff, int nC) {
  const int t = threadIdx.x;
  if (t < EBINS) {
    int run = eoff[t << EBIN_SHIFT];
    for (int c = 0; c < nC; ++c) {
      erunoff[t * nC + c] = run;
      run += echunkcnt[t * nC + c];
    }
  } else if (t < EBINS + NBINS) {
    int b = t - EBINS;
    int run = noff[b << NBIN_SHIFT];
    for (int c = 0; c < nC; ++c) {
      nrunoff[b * nC + c] = run;
      run += nchunkcnt[b * nC + c];
    }
  }
}

// Stage pass: each chunk writes its pairs into contiguous per-(bin,chunk) runs.
// LDS cursors only -- no global atomics, writes are localized contiguous runs.
__global__ __launch_bounds__(256) void stage_kernel(
    const int* __restrict__ node_idx, const int* __restrict__ edge_idx,
    const int* __restrict__ erunoff, const int* __restrict__ nrunoff,
    int2* __restrict__ epairs, int2* __restrict__ npairs, int nnz) {
  __shared__ int ecur[EBINS], ncur[NBINS];
  const int t = threadIdx.x;
  const int nC = gridDim.x;
  for (int b = t; b < EBINS; b += 256) ecur[b] = erunoff[b * nC + blockIdx.x];
  for (int b = t; b < NBINS; b += 256) ncur[b] = nrunoff[b * nC + blockIdx.x];
  __syncthreads();
  const int base = blockIdx.x * CHUNK;
  int end = base + CHUNK; if (end > nnz) end = nnz;
  for (int i = base + t; i < end; i += 256) {
    int e = edge_idx[i];
    int n = node_idx[i];
    int p = atomicAdd(&ecur[e >> EBIN_SHIFT], 1);
    epairs[p] = make_int2(e, n);
    int q = atomicAdd(&ncur[n >> NBIN_SHIFT], 1);
    npairs[q] = make_int2(n, e);
  }
}

// Final scatter: one block per bin; LDS rank counters; bin window read is
// contiguous (concatenated runs), writes confined to the bin's CSR window.
__global__ __launch_bounds__(256) void bin_scatter_kernel(
    const int2* __restrict__ epairs, const int2* __restrict__ npairs,
    const int* __restrict__ eoff, const int* __restrict__ noff,
    int* __restrict__ enbr, int* __restrict__ nnbr,
    int n_edges, int n_nodes) {
  __shared__ int cnt[256];
  const int bid = blockIdx.x;
  const int t = threadIdx.x;
  if (bid < EBINS) {
    int e0 = bid << EBIN_SHIFT;
    int e1 = e0 + (1 << EBIN_SHIFT); if (e1 > n_edges) e1 = n_edges;
    if (t < 128) cnt[t] = 0;
    __syncthreads();
    int beg = eoff[e0], end = eoff[e1];
    for (int j = beg + t; j < end; j += 256) {
      int2 p = epairs[j];
      int pos = eoff[p.x] + atomicAdd(&cnt[p.x & 127], 1);
      enbr[pos] = p.y;
    }
  } else {
    int b = bid - EBINS;
    int n0 = b << NBIN_SHIFT;
    int n1 = n0 + (1 << NBIN_SHIFT); if (n1 > n_nodes) n1 = n_nodes;
    cnt[t] = 0;
    __syncthreads();
    int beg = noff[n0], end = noff[n1];
    for (int j = beg + t; j < end; j += 256) {
      int2 p = npairs[j];
      int pos = noff[p.x] + atomicAdd(&cnt[p.x & 255], 1);
      nnbr[pos] = p.y;
    }
  }
}

// ---------------- GEMM1: xw16[M x 128] = x[M x 128] @ W[128 x 128], fp16 out ----------------

__global__ __launch_bounds__(256) void gemm1_kernel(
    const float* __restrict__ A, const float* __restrict__ B,
    __half* __restrict__ C16, int M) {
  __shared__ float xs[128][36];
  __shared__ float wsh[32][128];

  const int t = threadIdx.x;
  const int tx = t & 15;
  const int ty = t >> 4;
  const int bm = blockIdx.x * 128;

  float acc[8][8];
#pragma unroll
  for (int i = 0; i < 8; ++i)
#pragma unroll
    for (int j = 0; j < 8; ++j) acc[i][j] = 0.f;

  for (int kt = 0; kt < 4; ++kt) {
#pragma unroll
    for (int i = 0; i < 4; ++i) {
      int lin = i * 256 + t;
      int row = lin >> 3;
      int c4 = lin & 7;
      int grow = bm + row;
      float4 v = make_float4(0.f, 0.f, 0.f, 0.f);
      if (grow < M) v = *(const float4*)(A + (size_t)grow * 128 + kt * 32 + c4 * 4);
      *(float4*)&xs[row][c4 * 4] = v;
    }
#pragma unroll
    for (int i = 0; i < 4; ++i) {
      int lin = i * 256 + t;
      int k = lin >> 5;
      int c4 = lin & 31;
      *(float4*)&wsh[k][c4 * 4] = *(const float4*)(B + (size_t)(kt * 32 + k) * 128 + c4 * 4);
    }
    __syncthreads();

#pragma unroll 4
    for (int k = 0; k < 32; ++k) {
      float a[8], b[8];
#pragma unroll
      for (int j = 0; j < 4; ++j) {
        a[j]     = xs[ty * 4 + j][k];
        a[4 + j] = xs[ty * 4 + 64 + j][k];
      }
      float4 b0 = *(const float4*)&wsh[k][tx * 4];
      float4 b1 = *(const float4*)&wsh[k][tx * 4 + 64];
      b[0] = b0.x; b[1] = b0.y; b[2] = b0.z; b[3] = b0.w;
      b[4] = b1.x; b[5] = b1.y; b[6] = b1.z; b[7] = b1.w;
#pragma unroll
      for (int i = 0; i < 8; ++i)
#pragma unroll
        for (int j = 0; j < 8; ++j) acc[i][j] = fmaf(a[i], b[j], acc[i][j]);
    }
    __syncthreads();
  }

#pragma unroll
  for (int i = 0; i < 8; ++i) {
    int row = (i < 4) ? (ty * 4 + i) : (ty * 4 + 64 + (i - 4));
    int grow = bm + row;
    if (grow < M) {
      __half2* rp = (__half2*)(C16 + (size_t)grow * 128);
      rp[tx * 2]      = __floats2half2_rn(acc[i][0], acc[i][1]);
      rp[tx * 2 + 1]  = __floats2half2_rn(acc[i][2], acc[i][3]);
      rp[32 + tx * 2]     = __floats2half2_rn(acc[i][4], acc[i][5]);
      rp[32 + tx * 2 + 1] = __floats2half2_rn(acc[i][6], acc[i][7]);
    }
  }
}

// ---------------- Segment aggregation, F=128 fp16 (one wave per segment) ----------------

__global__ __launch_bounds__(256) void edge_agg128_kernel(
    const __half2* __restrict__ feat, const int* __restrict__ nbr,
    const int* __restrict__ off, __half2* __restrict__ outf, int nseg) {
  int w = (blockIdx.x * 256 + threadIdx.x) >> 6;
  int lane = threadIdx.x & 63;
  if (w >= nseg) return;
  int beg = off[w], end = off[w + 1];
  float ax = 0.f, ay = 0.f, bx = 0.f, by = 0.f;
  int j = beg;
  for (; j + 2 <= end; j += 2) {
    int n0 = nbr[j], n1 = nbr[j + 1];
    float2 v0 = __half22float2(feat[(size_t)n0 * 64 + lane]);
    float2 v1 = __half22float2(feat[(size_t)n1 * 64 + lane]);
    ax += v0.x; ay += v0.y; bx += v1.x; by += v1.y;
  }
  if (j < end) {
    float2 v = __half22float2(feat[(size_t)nbr[j] * 64 + lane]);
    ax += v.x; ay += v.y;
  }
  float inv = (end > beg) ? 1.f / (float)(end - beg) : 0.f;
  outf[(size_t)w * 64 + lane] = __floats2half2_rn((ax + bx) * inv, (ay + by) * inv);
}

__global__ __launch_bounds__(256) void node_agg128_kernel(
    const __half2* __restrict__ feat, const int* __restrict__ nbr,
    const int* __restrict__ off, const float* __restrict__ bias,
    __half2* __restrict__ outf, int nseg) {
  int w = (blockIdx.x * 256 + threadIdx.x) >> 6;
  int lane = threadIdx.x & 63;
  if (w >= nseg) return;
  int beg = off[w], end = off[w + 1];
  float ax = 0.f, ay = 0.f, bx = 0.f, by = 0.f;
  int j = beg;
  for (; j + 2 <= end; j += 2) {
    int e0 = nbr[j], e1 = nbr[j + 1];
    float2 v0 = __half22float2(feat[(size_t)e0 * 64 + lane]);
    float2 v1 = __half22float2(feat[(size_t)e1 * 64 + lane]);
    ax += v0.x; ay += v0.y; bx += v1.x; by += v1.y;
  }
  if (j < end) {
    float2 v = __half22float2(feat[(size_t)nbr[j] * 64 + lane]);
    ax += v.x; ay += v.y;
  }
  float inv = (end > beg) ? 1.f / (float)(end - beg) : 0.f;
  float2 b = *(const float2*)(bias + lane * 2);
  float hx = fmaxf((ax + bx) * inv + b.x, 0.f);   // + b1, ReLU
  float hy = fmaxf((ay + by) * inv + b.y, 0.f);
  outf[(size_t)w * 64 + lane] = __floats2half2_rn(hx, hy);
}

// ---------------- GEMM2: hw2[M x 16] = h16[M x 128] @ W2[128 x 16] ----------------

__global__ __launch_bounds__(256) void gemm2_kernel(
    const __half* __restrict__ H16, const float* __restrict__ W2,
    float* __restrict__ O, int M) {
  __shared__ float ws2[128 * 16];
  const int t = threadIdx.x;
#pragma unroll
  for (int i = 0; i < 8; ++i) ws2[i * 256 + t] = W2[i * 256 + t];
  __syncthreads();

  int r0 = blockIdx.x * 512 + t;
  int r1 = r0 + 256;
  bool v0 = r0 < M, v1 = r1 < M;
  const __half2* h0 = (const __half2*)(H16 + (size_t)r0 * 128);
  const __half2* h1 = (const __half2*)(H16 + (size_t)r1 * 128);

  float4 acc0[4], acc1[4];
#pragma unroll
  for (int q = 0; q < 4; ++q) {
    acc0[q] = make_float4(0.f, 0.f, 0.f, 0.f);
    acc1[q] = make_float4(0.f, 0.f, 0.f, 0.f);
  }

  for (int k4 = 0; k4 < 32; ++k4) {
    float2 f00 = make_float2(0.f, 0.f), f01 = make_float2(0.f, 0.f);
    float2 f10 = make_float2(0.f, 0.f), f11 = make_float2(0.f, 0.f);
    if (v0) { f00 = __half22float2(h0[2 * k4]); f01 = __half22float2(h0[2 * k4 + 1]); }
    if (v1) { f10 = __half22float2(h1[2 * k4]); f11 = __half22float2(h1[2 * k4 + 1]); }
    const float a0s[4] = {f00.x, f00.y, f01.x, f01.y};
    const float a1s[4] = {f10.x, f10.y, f11.x, f11.y};
#pragma unroll
    for (int j = 0; j < 4; ++j) {
      int k = k4 * 4 + j;
#pragma unroll
      for (int q = 0; q < 4; ++q) {
        float4 b = *(const float4*)&ws2[k * 16 + q * 4];
        acc0[q].x = fmaf(a0s[j], b.x, acc0[q].x);
        acc0[q].y = fmaf(a0s[j], b.y, acc0[q].y);
        acc0[q].z = fmaf(a0s[j], b.z, acc0[q].z);
        acc0[q].w = fmaf(a0s[j], b.w, acc0[q].w);
        acc1[q].x = fmaf(a1s[j], b.x, acc1[q].x);
        acc1[q].y = fmaf(a1s[j], b.y, acc1[q].y);
        acc1[q].z = fmaf(a1s[j], b.z, acc1[q].z);
        acc1[q].w = fmaf(a1s[j], b.w, acc1[q].w);
      }
    }
  }
  if (v0) {
#pragma unroll
    for (int q = 0; q < 4; ++q) *(float4*)(O + (size_t)r0 * 16 + q * 4) = acc0[q];
  }
  if (v1) {
#pragma unroll
    for (int q = 0; q < 4; ++q) *(float4*)(O + (size_t)r1 * 16 + q * 4) = acc1[q];
  }
}

// ---------------- Segment aggregation, F=16 (fp32) ----------------

__global__ __launch_bounds__(256) void edge_agg16_kernel(
    const float* __restrict__ feat, const int* __restrict__ nbr,
    const int* __restrict__ off, float* __restrict__ outf, int nseg) {
  int gid = blockIdx.x * 256 + threadIdx.x;
  int seg = gid >> 4;
  int c = gid & 15;
  if (seg >= nseg) return;
  int beg = off[seg], end = off[seg + 1];
  float acc = 0.f;
  for (int j = beg; j < end; ++j) acc += feat[(size_t)nbr[j] * 16 + c];
  float inv = (end > beg) ? 1.f / (float)(end - beg) : 0.f;
  outf[(size_t)seg * 16 + c] = acc * inv;
}

__global__ __launch_bounds__(256) void node_agg16_kernel(
    const float* __restrict__ feat, const int* __restrict__ nbr,
    const int* __restrict__ off, const float* __restrict__ bias,
    float* __restrict__ outf, int nseg) {
  int gid = blockIdx.x * 256 + threadIdx.x;
  int seg = gid >> 4;
  int c = gid & 15;
  if (seg >= nseg) return;
  int beg = off[seg], end = off[seg + 1];
  float acc = 0.f;
  for (int j = beg; j < end; ++j) acc += feat[(size_t)nbr[j] * 16 + c];
  float inv = (end > beg) ? 1.f / (float)(end - beg) : 0.f;
  outf[(size_t)seg * 16 + c] = acc * inv + bias[c];
}

// ---------------- launch ----------------

extern "C" void kernel_launch(void* const* d_in, const int* in_sizes, int n_in,
                              void* d_out, int out_size, void* d_ws, size_t ws_size,
                              hipStream_t stream) {
  const float* x        = (const float*)d_in[0];
  const int*   node_idx = (const int*)d_in[1];
  const int*   edge_idx = (const int*)d_in[2];
  const float* W1 = (const float*)d_in[4];
  const float* b1 = (const float*)d_in[5];
  const float* W2 = (const float*)d_in[6];
  const float* b2 = (const float*)d_in[7];
  float* out = (float*)d_out;

  const int n_nodes = in_sizes[0] / F1;  // 100000
  const int nnz     = in_sizes[1];       // 1600000
  const int n_edges = N_EDGES_C;         // 50000
  const int nC      = (nnz + CHUNK - 1) / CHUNK;   // 98

  char* ws = (char*)d_ws;
  // layout (bytes), high-water ~88.3 MB (ws >= 97.4 MB known-safe from R1):
  int2*   epairs = (int2*)(ws + 0);            // 12.8M transient (consumed by bin_scatter)
  int2*   npairs = (int2*)(ws + 12800000);     // 12.8M transient
  __half* h16    = (__half*)(ws + 0);          // 25.6M (written by nagg128, after bin_scatter)
  __half* xw16   = (__half*)(ws + 25600000);   // 25.6M
  __half* ef16   = (__half*)(ws + 51200000);   // 12.8M
  float*  hw2    = (float*)(ws + 64000000);    //  6.4M
  float*  ef2    = (float*)(ws + 70400000);    //  3.2M
  int*    enbr   = (int*)(ws + 73600000);      //  6.4M
  int*    nnbr   = (int*)(ws + 80000000);      //  6.4M
  int*    ecnt   = (int*)(ws + 86400000);      //  200,000
  int*    ncnt   = (int*)(ws + 86600000);      //  400,000
  int*    eoff   = (int*)(ws + 87000000);      //  200,004
  int*    noff   = (int*)(ws + 87200016);      //  400,004
  int*    echunkcnt = (int*)(ws + 87600024);   //  153,272 (EBINS*nC)
  int*    nchunkcnt = (int*)(ws + 87753296);   //  153,272
  int*    erunoff   = (int*)(ws + 87906568);   //  153,272
  int*    nrunoff   = (int*)(ws + 88059840);   //  153,272 -> end 88,213,112

  // zero only the per-segment histograms (ws is re-poisoned 0xAA each call)
  hipMemsetAsync(ecnt, 0, 600000, stream);

  hist_chunk_kernel<<<nC, 256, 0, stream>>>(node_idx, edge_idx, ncnt, ecnt,
                                            echunkcnt, nchunkcnt, nnz);
  scan_excl_kernel<<<1, 1024, 0, stream>>>(ecnt, eoff, n_edges);
  scan_excl_kernel<<<1, 1024, 0, stream>>>(ncnt, noff, n_nodes);
  runoff_kernel<<<1, 1024, 0, stream>>>(eoff, noff, echunkcnt, nchunkcnt,
                                        erunoff, nrunoff, nC);
  stage_kernel<<<nC, 256, 0, stream>>>(node_idx, edge_idx, erunoff, nrunoff,
                                       epairs, npairs, nnz);
  bin_scatter_kernel<<<EBINS + NBINS, 256, 0, stream>>>(epairs, npairs, eoff, noff,
                                                        enbr, nnbr, n_edges, n_nodes);

  // layer 1 (fp16 message path)
  gemm1_kernel<<<(n_nodes + 127) / 128, 256, 0, stream>>>(x, W1, xw16, n_nodes);
  edge_agg128_kernel<<<(n_edges * 64 + 255) / 256, 256, 0, stream>>>(
      (const __half2*)xw16, enbr, eoff, (__half2*)ef16, n_edges);
  node_agg128_kernel<<<(n_nodes * 64 + 255) / 256, 256, 0, stream>>>(
      (const __half2*)ef16, nnbr, noff, b1, (__half2*)h16, n_nodes);

  // layer 2
  gemm2_kernel<<<(n_nodes + 511) / 512, 256, 0, stream>>>(h16, W2, hw2, n_nodes);
  edge_agg16_kernel<<<(n_edges * 16 + 255) / 256, 256, 0, stream>>>(hw2, enbr, eoff, ef2, n_edges);
  node_agg16_kernel<<<(n_nodes * 16 + 255) / 256, 256, 0, stream>>>(ef2, nnbr, noff, b2, out, n_nodes);
}

// Round 5
// 772.998 us; speedup vs baseline: 1.4860x; 1.2860x over previous
//
#include <hip/hip_runtime.h>
#include <hip/hip_fp16.h>

// Problem constants: N_NODES=100000, N_EDGES=50000, NNZ=1600000, dims 128->128->16, fp32 I/O.
// Internal message path (xw, e_feat, h) stored fp16, accumulated fp32.

#define N_EDGES_C 50000
#define F1 128
#define F2 16
#define CHUNK 16384               // elements per chunk for the counting sort
#define EBIN_SHIFT 7              // 128 edges per bin
#define NBIN_SHIFT 8              // 256 nodes per bin
#define EBINS 391                 // ceil(50000/128)
#define NBINS 391                 // ceil(100000/256)
#define SCAN_BLK 1024             // elements per block in the hierarchical scan

// ---------------- CSR build: chunked counting sort ----------------

// Per-edge/node histogram (global atomics) + per-(chunk,bin) counts (LDS).
__global__ __launch_bounds__(256) void hist_chunk_kernel(
    const int* __restrict__ node_idx, const int* __restrict__ edge_idx,
    int* __restrict__ ncnt, int* __restrict__ ecnt,
    int* __restrict__ echunkcnt, int* __restrict__ nchunkcnt, int nnz) {
  __shared__ int ebc[EBINS], nbc[NBINS];
  const int t = threadIdx.x;
  for (int b = t; b < EBINS; b += 256) ebc[b] = 0;
  for (int b = t; b < NBINS; b += 256) nbc[b] = 0;
  __syncthreads();
  const int base = blockIdx.x * CHUNK;
  int end = base + CHUNK; if (end > nnz) end = nnz;
  for (int i = base + t; i < end; i += 256) {
    int e = edge_idx[i];
    int n = node_idx[i];
    atomicAdd(&ecnt[e], 1);
    atomicAdd(&ncnt[n], 1);
    atomicAdd(&ebc[e >> EBIN_SHIFT], 1);
    atomicAdd(&nbc[n >> NBIN_SHIFT], 1);
  }
  __syncthreads();
  const int nC = gridDim.x;
  for (int b = t; b < EBINS; b += 256) echunkcnt[b * nC + blockIdx.x] = ebc[b];
  for (int b = t; b < NBINS; b += 256) nchunkcnt[b * nC + blockIdx.x] = nbc[b];
}

// ---------------- Hierarchical exclusive scan (both arrays in one grid) ----------------

// Phase 1: per-block sums.
__global__ __launch_bounds__(256) void scan_phase1_kernel(
    const int* __restrict__ ecnt, const int* __restrict__ ncnt,
    int* __restrict__ epart, int* __restrict__ npart,
    int nE, int nN, int nbE) {
  __shared__ int red[256];
  const int t = threadIdx.x;
  const int b = blockIdx.x;
  const int* src; int n; int* dst; int bb;
  if (b < nbE) { src = ecnt; n = nE; dst = epart; bb = b; }
  else         { src = ncnt; n = nN; dst = npart; bb = b - nbE; }
  int base = bb * SCAN_BLK + t * 4;
  int s = 0;
#pragma unroll
  for (int j = 0; j < 4; ++j) { int i = base + j; if (i < n) s += src[i]; }
  red[t] = s;
  __syncthreads();
  for (int d = 128; d > 0; d >>= 1) {
    if (t < d) red[t] += red[t + d];
    __syncthreads();
  }
  if (t == 0) dst[bb] = red[0];
}

// Phase 2: single block scans both partial arrays (<=128 each) -> exclusive offsets.
__global__ __launch_bounds__(256) void scan_phase2_kernel(
    int* __restrict__ epart, int* __restrict__ npart, int nbE, int nbN) {
  __shared__ int se[128], sn[128];
  const int t = threadIdx.x;
  if (t < 128) {
    se[t] = (t < nbE) ? epart[t] : 0;
    sn[t] = (t < nbN) ? npart[t] : 0;
  }
  __syncthreads();
  for (int d = 1; d < 128; d <<= 1) {
    int ve = 0, vn = 0;
    if (t < 128 && t >= d) { ve = se[t - d]; vn = sn[t - d]; }
    __syncthreads();
    if (t < 128) { se[t] += ve; sn[t] += vn; }
    __syncthreads();
  }
  if (t < 128) {
    int e_ex = (t > 0) ? se[t - 1] : 0;
    int n_ex = (t > 0) ? sn[t - 1] : 0;
    if (t < nbE) epart[t] = e_ex;
    if (t < nbN) npart[t] = n_ex;
  }
}

// Phase 3: block-local exclusive scan + block offset -> off[]; last block writes off[n].
__global__ __launch_bounds__(256) void scan_phase3_kernel(
    const int* __restrict__ ecnt, const int* __restrict__ ncnt,
    const int* __restrict__ epart, const int* __restrict__ npart,
    int* __restrict__ eoff, int* __restrict__ noff,
    int nE, int nN, int nbE, int nbN) {
  __shared__ int red[256];
  const int t = threadIdx.x;
  const int b = blockIdx.x;
  const int* src; const int* part; int n; int* off; int bb; int nb;
  if (b < nbE) { src = ecnt; part = epart; n = nE; off = eoff; bb = b; nb = nbE; }
  else         { src = ncnt; part = npart; n = nN; off = noff; bb = b - nbE; nb = nbN; }
  int base = bb * SCAN_BLK + t * 4;
  int v[4]; int s = 0;
#pragma unroll
  for (int j = 0; j < 4; ++j) { int i = base + j; v[j] = (i < n) ? src[i] : 0; s += v[j]; }
  red[t] = s;
  __syncthreads();
  for (int d = 1; d < 256; d <<= 1) {
    int x = (t >= d) ? red[t - d] : 0;
    __syncthreads();
    red[t] += x;
    __syncthreads();
  }
  int toff = part[bb] + ((t > 0) ? red[t - 1] : 0);
#pragma unroll
  for (int j = 0; j < 4; ++j) {
    int i = base + j;
    if (i < n) off[i] = toff;
    toff += v[j];
  }
  if (bb == nb - 1 && t == 255) off[n] = part[bb] + red[255];
}

// Per-bin serial scan over chunks: run start offsets for each (bin, chunk).
__global__ __launch_bounds__(1024) void runoff_kernel(
    const int* __restrict__ eoff, const int* __restrict__ noff,
    const int* __restrict__ echunkcnt, const int* __restrict__ nchunkcnt,
    int* __restrict__ erunoff, int* __restrict__ nrunoff, int nC) {
  const int t = threadIdx.x;
  if (t < EBINS) {
    int run = eoff[t << EBIN_SHIFT];
    for (int c = 0; c < nC; ++c) {
      erunoff[t * nC + c] = run;
      run += echunkcnt[t * nC + c];
    }
  } else if (t < EBINS + NBINS) {
    int b = t - EBINS;
    int run = noff[b << NBIN_SHIFT];
    for (int c = 0; c < nC; ++c) {
      nrunoff[b * nC + c] = run;
      run += nchunkcnt[b * nC + c];
    }
  }
}

// Stage pass: each chunk writes its pairs into contiguous per-(bin,chunk) runs.
__global__ __launch_bounds__(256) void stage_kernel(
    const int* __restrict__ node_idx, const int* __restrict__ edge_idx,
    const int* __restrict__ erunoff, const int* __restrict__ nrunoff,
    int2* __restrict__ epairs, int2* __restrict__ npairs, int nnz) {
  __shared__ int ecur[EBINS], ncur[NBINS];
  const int t = threadIdx.x;
  const int nC = gridDim.x;
  for (int b = t; b < EBINS; b += 256) ecur[b] = erunoff[b * nC + blockIdx.x];
  for (int b = t; b < NBINS; b += 256) ncur[b] = nrunoff[b * nC + blockIdx.x];
  __syncthreads();
  const int base = blockIdx.x * CHUNK;
  int end = base + CHUNK; if (end > nnz) end = nnz;
  for (int i = base + t; i < end; i += 256) {
    int e = edge_idx[i];
    int n = node_idx[i];
    int p = atomicAdd(&ecur[e >> EBIN_SHIFT], 1);
    epairs[p] = make_int2(e, n);
    int q = atomicAdd(&ncur[n >> NBIN_SHIFT], 1);
    npairs[q] = make_int2(n, e);
  }
}

// Final scatter: one block per bin; LDS rank counters.
__global__ __launch_bounds__(256) void bin_scatter_kernel(
    const int2* __restrict__ epairs, const int2* __restrict__ npairs,
    const int* __restrict__ eoff, const int* __restrict__ noff,
    int* __restrict__ enbr, int* __restrict__ nnbr,
    int n_edges, int n_nodes) {
  __shared__ int cnt[256];
  const int bid = blockIdx.x;
  const int t = threadIdx.x;
  if (bid < EBINS) {
    int e0 = bid << EBIN_SHIFT;
    int e1 = e0 + (1 << EBIN_SHIFT); if (e1 > n_edges) e1 = n_edges;
    if (t < 128) cnt[t] = 0;
    __syncthreads();
    int beg = eoff[e0], end = eoff[e1];
    for (int j = beg + t; j < end; j += 256) {
      int2 p = epairs[j];
      int pos = eoff[p.x] + atomicAdd(&cnt[p.x & 127], 1);
      enbr[pos] = p.y;
    }
  } else {
    int b = bid - EBINS;
    int n0 = b << NBIN_SHIFT;
    int n1 = n0 + (1 << NBIN_SHIFT); if (n1 > n_nodes) n1 = n_nodes;
    cnt[t] = 0;
    __syncthreads();
    int beg = noff[n0], end = noff[n1];
    for (int j = beg + t; j < end; j += 256) {
      int2 p = npairs[j];
      int pos = noff[p.x] + atomicAdd(&cnt[p.x & 255], 1);
      nnbr[pos] = p.y;
    }
  }
}

// ---------------- GEMM1: xw16[M x 128] = x[M x 128] @ W[128 x 128], fp16 out ----------------

__global__ __launch_bounds__(256) void gemm1_kernel(
    const float* __restrict__ A, const float* __restrict__ B,
    __half* __restrict__ C16, int M) {
  __shared__ float xs[128][36];
  __shared__ float wsh[32][128];

  const int t = threadIdx.x;
  const int tx = t & 15;
  const int ty = t >> 4;
  const int bm = blockIdx.x * 128;

  float acc[8][8];
#pragma unroll
  for (int i = 0; i < 8; ++i)
#pragma unroll
    for (int j = 0; j < 8; ++j) acc[i][j] = 0.f;

  for (int kt = 0; kt < 4; ++kt) {
#pragma unroll
    for (int i = 0; i < 4; ++i) {
      int lin = i * 256 + t;
      int row = lin >> 3;
      int c4 = lin & 7;
      int grow = bm + row;
      float4 v = make_float4(0.f, 0.f, 0.f, 0.f);
      if (grow < M) v = *(const float4*)(A + (size_t)grow * 128 + kt * 32 + c4 * 4);
      *(float4*)&xs[row][c4 * 4] = v;
    }
#pragma unroll
    for (int i = 0; i < 4; ++i) {
      int lin = i * 256 + t;
      int k = lin >> 5;
      int c4 = lin & 31;
      *(float4*)&wsh[k][c4 * 4] = *(const float4*)(B + (size_t)(kt * 32 + k) * 128 + c4 * 4);
    }
    __syncthreads();

#pragma unroll 4
    for (int k = 0; k < 32; ++k) {
      float a[8], b[8];
#pragma unroll
      for (int j = 0; j < 4; ++j) {
        a[j]     = xs[ty * 4 + j][k];
        a[4 + j] = xs[ty * 4 + 64 + j][k];
      }
      float4 b0 = *(const float4*)&wsh[k][tx * 4];
      float4 b1 = *(const float4*)&wsh[k][tx * 4 + 64];
      b[0] = b0.x; b[1] = b0.y; b[2] = b0.z; b[3] = b0.w;
      b[4] = b1.x; b[5] = b1.y; b[6] = b1.z; b[7] = b1.w;
#pragma unroll
      for (int i = 0; i < 8; ++i)
#pragma unroll
        for (int j = 0; j < 8; ++j) acc[i][j] = fmaf(a[i], b[j], acc[i][j]);
    }
    __syncthreads();
  }

#pragma unroll
  for (int i = 0; i < 8; ++i) {
    int row = (i < 4) ? (ty * 4 + i) : (ty * 4 + 64 + (i - 4));
    int grow = bm + row;
    if (grow < M) {
      __half2* rp = (__half2*)(C16 + (size_t)grow * 128);
      rp[tx * 2]      = __floats2half2_rn(acc[i][0], acc[i][1]);
      rp[tx * 2 + 1]  = __floats2half2_rn(acc[i][2], acc[i][3]);
      rp[32 + tx * 2]     = __floats2half2_rn(acc[i][4], acc[i][5]);
      rp[32 + tx * 2 + 1] = __floats2half2_rn(acc[i][6], acc[i][7]);
    }
  }
}

// ---------------- Segment aggregation, F=128 fp16 (one wave per segment) ----------------

__global__ __launch_bounds__(256) void edge_agg128_kernel(
    const __half2* __restrict__ feat, const int* __restrict__ nbr,
    const int* __restrict__ off, __half2* __restrict__ outf, int nseg) {
  int w = (blockIdx.x * 256 + threadIdx.x) >> 6;
  int lane = threadIdx.x & 63;
  if (w >= nseg) return;
  int beg = off[w], end = off[w + 1];
  float ax = 0.f, ay = 0.f, bx = 0.f, by = 0.f;
  int j = beg;
  for (; j + 2 <= end; j += 2) {
    int n0 = nbr[j], n1 = nbr[j + 1];
    float2 v0 = __half22float2(feat[(size_t)n0 * 64 + lane]);
    float2 v1 = __half22float2(feat[(size_t)n1 * 64 + lane]);
    ax += v0.x; ay += v0.y; bx += v1.x; by += v1.y;
  }
  if (j < end) {
    float2 v = __half22float2(feat[(size_t)nbr[j] * 64 + lane]);
    ax += v.x; ay += v.y;
  }
  float inv = (end > beg) ? 1.f / (float)(end - beg) : 0.f;
  outf[(size_t)w * 64 + lane] = __floats2half2_rn((ax + bx) * inv, (ay + by) * inv);
}

__global__ __launch_bounds__(256) void node_agg128_kernel(
    const __half2* __restrict__ feat, const int* __restrict__ nbr,
    const int* __restrict__ off, const float* __restrict__ bias,
    __half2* __restrict__ outf, int nseg) {
  int w = (blockIdx.x * 256 + threadIdx.x) >> 6;
  int lane = threadIdx.x & 63;
  if (w >= nseg) return;
  int beg = off[w], end = off[w + 1];
  float ax = 0.f, ay = 0.f, bx = 0.f, by = 0.f;
  int j = beg;
  for (; j + 2 <= end; j += 2) {
    int e0 = nbr[j], e1 = nbr[j + 1];
    float2 v0 = __half22float2(feat[(size_t)e0 * 64 + lane]);
    float2 v1 = __half22float2(feat[(size_t)e1 * 64 + lane]);
    ax += v0.x; ay += v0.y; bx += v1.x; by += v1.y;
  }
  if (j < end) {
    float2 v = __half22float2(feat[(size_t)nbr[j] * 64 + lane]);
    ax += v.x; ay += v.y;
  }
  float inv = (end > beg) ? 1.f / (float)(end - beg) : 0.f;
  float2 b = *(const float2*)(bias + lane * 2);
  float hx = fmaxf((ax + bx) * inv + b.x, 0.f);   // + b1, ReLU
  float hy = fmaxf((ay + by) * inv + b.y, 0.f);
  outf[(size_t)w * 64 + lane] = __floats2half2_rn(hx, hy);
}

// ---------------- GEMM2: hw2[M x 16] = h16[M x 128] @ W2[128 x 16] ----------------

__global__ __launch_bounds__(256) void gemm2_kernel(
    const __half* __restrict__ H16, const float* __restrict__ W2,
    float* __restrict__ O, int M) {
  __shared__ float ws2[128 * 16];
  const int t = threadIdx.x;
#pragma unroll
  for (int i = 0; i < 8; ++i) ws2[i * 256 + t] = W2[i * 256 + t];
  __syncthreads();

  int r0 = blockIdx.x * 512 + t;
  int r1 = r0 + 256;
  bool v0 = r0 < M, v1 = r1 < M;
  const __half2* h0 = (const __half2*)(H16 + (size_t)r0 * 128);
  const __half2* h1 = (const __half2*)(H16 + (size_t)r1 * 128);

  float4 acc0[4], acc1[4];
#pragma unroll
  for (int q = 0; q < 4; ++q) {
    acc0[q] = make_float4(0.f, 0.f, 0.f, 0.f);
    acc1[q] = make_float4(0.f, 0.f, 0.f, 0.f);
  }

  for (int k4 = 0; k4 < 32; ++k4) {
    float2 f00 = make_float2(0.f, 0.f), f01 = make_float2(0.f, 0.f);
    float2 f10 = make_float2(0.f, 0.f), f11 = make_float2(0.f, 0.f);
    if (v0) { f00 = __half22float2(h0[2 * k4]); f01 = __half22float2(h0[2 * k4 + 1]); }
    if (v1) { f10 = __half22float2(h1[2 * k4]); f11 = __half22float2(h1[2 * k4 + 1]); }
    const float a0s[4] = {f00.x, f00.y, f01.x, f01.y};
    const float a1s[4] = {f10.x, f10.y, f11.x, f11.y};
#pragma unroll
    for (int j = 0; j < 4; ++j) {
      int k = k4 * 4 + j;
#pragma unroll
      for (int q = 0; q < 4; ++q) {
        float4 b = *(const float4*)&ws2[k * 16 + q * 4];
        acc0[q].x = fmaf(a0s[j], b.x, acc0[q].x);
        acc0[q].y = fmaf(a0s[j], b.y, acc0[q].y);
        acc0[q].z = fmaf(a0s[j], b.z, acc0[q].z);
        acc0[q].w = fmaf(a0s[j], b.w, acc0[q].w);
        acc1[q].x = fmaf(a1s[j], b.x, acc1[q].x);
        acc1[q].y = fmaf(a1s[j], b.y, acc1[q].y);
        acc1[q].z = fmaf(a1s[j], b.z, acc1[q].z);
        acc1[q].w = fmaf(a1s[j], b.w, acc1[q].w);
      }
    }
  }
  if (v0) {
#pragma unroll
    for (int q = 0; q < 4; ++q) *(float4*)(O + (size_t)r0 * 16 + q * 4) = acc0[q];
  }
  if (v1) {
#pragma unroll
    for (int q = 0; q < 4; ++q) *(float4*)(O + (size_t)r1 * 16 + q * 4) = acc1[q];
  }
}

// ---------------- Segment aggregation, F=16 (fp32) ----------------

__global__ __launch_bounds__(256) void edge_agg16_kernel(
    const float* __restrict__ feat, const int* __restrict__ nbr,
    const int* __restrict__ off, float* __restrict__ outf, int nseg) {
  int gid = blockIdx.x * 256 + threadIdx.x;
  int seg = gid >> 4;
  int c = gid & 15;
  if (seg >= nseg) return;
  int beg = off[seg], end = off[seg + 1];
  float acc = 0.f;
  for (int j = beg; j < end; ++j) acc += feat[(size_t)nbr[j] * 16 + c];
  float inv = (end > beg) ? 1.f / (float)(end - beg) : 0.f;
  outf[(size_t)seg * 16 + c] = acc * inv;
}

__global__ __launch_bounds__(256) void node_agg16_kernel(
    const float* __restrict__ feat, const int* __restrict__ nbr,
    const int* __restrict__ off, const float* __restrict__ bias,
    float* __restrict__ outf, int nseg) {
  int gid = blockIdx.x * 256 + threadIdx.x;
  int seg = gid >> 4;
  int c = gid & 15;
  if (seg >= nseg) return;
  int beg = off[seg], end = off[seg + 1];
  float acc = 0.f;
  for (int j = beg; j < end; ++j) acc += feat[(size_t)nbr[j] * 16 + c];
  float inv = (end > beg) ? 1.f / (float)(end - beg) : 0.f;
  outf[(size_t)seg * 16 + c] = acc * inv + bias[c];
}

// ---------------- launch ----------------

extern "C" void kernel_launch(void* const* d_in, const int* in_sizes, int n_in,
                              void* d_out, int out_size, void* d_ws, size_t ws_size,
                              hipStream_t stream) {
  const float* x        = (const float*)d_in[0];
  const int*   node_idx = (const int*)d_in[1];
  const int*   edge_idx = (const int*)d_in[2];
  const float* W1 = (const float*)d_in[4];
  const float* b1 = (const float*)d_in[5];
  const float* W2 = (const float*)d_in[6];
  const float* b2 = (const float*)d_in[7];
  float* out = (float*)d_out;

  const int n_nodes = in_sizes[0] / F1;  // 100000
  const int nnz     = in_sizes[1];       // 1600000
  const int n_edges = N_EDGES_C;         // 50000
  const int nC      = (nnz + CHUNK - 1) / CHUNK;   // 98
  const int nbE     = (n_edges + SCAN_BLK - 1) / SCAN_BLK;   // 49
  const int nbN     = (n_nodes + SCAN_BLK - 1) / SCAN_BLK;   // 98

  char* ws = (char*)d_ws;
  // layout (bytes), high-water ~88.3 MB:
  int2*   epairs = (int2*)(ws + 0);            // 12.8M transient (consumed by bin_scatter)
  int2*   npairs = (int2*)(ws + 12800000);     // 12.8M transient
  __half* h16    = (__half*)(ws + 0);          // 25.6M (written by nagg128, after bin_scatter)
  __half* xw16   = (__half*)(ws + 25600000);   // 25.6M
  __half* ef16   = (__half*)(ws + 51200000);   // 12.8M
  float*  hw2    = (float*)(ws + 64000000);    //  6.4M
  float*  ef2    = (float*)(ws + 70400000);    //  3.2M
  int*    enbr   = (int*)(ws + 73600000);      //  6.4M
  int*    nnbr   = (int*)(ws + 80000000);      //  6.4M
  int*    ecnt   = (int*)(ws + 86400000);      //  200,000
  int*    ncnt   = (int*)(ws + 86600000);      //  400,000
  int*    eoff   = (int*)(ws + 87000000);      //  200,004
  int*    noff   = (int*)(ws + 87200016);      //  400,004
  int*    echunkcnt = (int*)(ws + 87600024);   //  153,272 (EBINS*nC)
  int*    nchunkcnt = (int*)(ws + 87753296);   //  153,272
  int*    erunoff   = (int*)(ws + 87906568);   //  153,272
  int*    nrunoff   = (int*)(ws + 88059840);   //  153,272
  int*    epart     = (int*)(ws + 88213120);   //  512 (128 ints)
  int*    npart     = (int*)(ws + 88213632);   //  512 -> end 88,214,144

  // zero only the per-segment histograms (ws is re-poisoned 0xAA each call)
  hipMemsetAsync(ecnt, 0, 600000, stream);

  hist_chunk_kernel<<<nC, 256, 0, stream>>>(node_idx, edge_idx, ncnt, ecnt,
                                            echunkcnt, nchunkcnt, nnz);
  scan_phase1_kernel<<<nbE + nbN, 256, 0, stream>>>(ecnt, ncnt, epart, npart,
                                                    n_edges, n_nodes, nbE);
  scan_phase2_kernel<<<1, 256, 0, stream>>>(epart, npart, nbE, nbN);
  scan_phase3_kernel<<<nbE + nbN, 256, 0, stream>>>(ecnt, ncnt, epart, npart,
                                                    eoff, noff, n_edges, n_nodes, nbE, nbN);
  runoff_kernel<<<1, 1024, 0, stream>>>(eoff, noff, echunkcnt, nchunkcnt,
                                        erunoff, nrunoff, nC);
  stage_kernel<<<nC, 256, 0, stream>>>(node_idx, edge_idx, erunoff, nrunoff,
                                       epairs, npairs, nnz);
  bin_scatter_kernel<<<EBINS + NBINS, 256, 0, stream>>>(epairs, npairs, eoff, noff,
                                                        enbr, nnbr, n_edges, n_nodes);

  // layer 1 (fp16 message path)
  gemm1_kernel<<<(n_nodes + 127) / 128, 256, 0, stream>>>(x, W1, xw16, n_nodes);
  edge_agg128_kernel<<<(n_edges * 64 + 255) / 256, 256, 0, stream>>>(
      (const __half2*)xw16, enbr, eoff, (__half2*)ef16, n_edges);
  node_agg128_kernel<<<(n_nodes * 64 + 255) / 256, 256, 0, stream>>>(
      (const __half2*)ef16, nnbr, noff, b1, (__half2*)h16, n_nodes);

  // layer 2
  gemm2_kernel<<<(n_nodes + 511) / 512, 256, 0, stream>>>(h16, W2, hw2, n_nodes);
  edge_agg16_kernel<<<(n_edges * 16 + 255) / 256, 256, 0, stream>>>(hw2, enbr, eoff, ef2, n_edges);
  node_agg16_kernel<<<(n_nodes * 16 + 255) / 256, 256, 0, stream>>>(ef2, nnbr, noff, b2, out, n_nodes);
}

// Round 6
// 746.589 us; speedup vs baseline: 1.5386x; 1.0354x over previous
//
#include <hip/hip_runtime.h>
#include <hip/hip_fp16.h>

// Problem constants: N_NODES=100000, N_EDGES=50000, NNZ=1600000, dims 128->128->16, fp32 I/O.
// Internal message path (xw, e_feat, h) stored fp16, accumulated fp32.
// CSR build: counting sort with NO global atomics anywhere (LDS histograms only).

#define N_EDGES_C 50000
#define F1 128
#define F2 16
#define CHUNK 4096                // elements per chunk (391 chunks -> good occupancy)
#define EBIN_SHIFT 7              // 128 edges per bin
#define NBIN_SHIFT 8              // 256 nodes per bin
#define EBINS 391                 // ceil(50000/128)
#define NBINS 391                 // ceil(100000/256)

// ---------------- CSR build ----------------

// Per-(chunk,bin) counts via LDS histograms. No global atomics.
__global__ __launch_bounds__(256) void hist_chunk_kernel(
    const int* __restrict__ node_idx, const int* __restrict__ edge_idx,
    int* __restrict__ echunkcnt, int* __restrict__ nchunkcnt, int nnz) {
  __shared__ int ebc[EBINS], nbc[NBINS];
  const int t = threadIdx.x;
  for (int b = t; b < EBINS; b += 256) ebc[b] = 0;
  for (int b = t; b < NBINS; b += 256) nbc[b] = 0;
  __syncthreads();
  const int base = blockIdx.x * CHUNK;
  int end = base + CHUNK; if (end > nnz) end = nnz;
  for (int i = base + t; i < end; i += 256) {
    atomicAdd(&ebc[edge_idx[i] >> EBIN_SHIFT], 1);
    atomicAdd(&nbc[node_idx[i] >> NBIN_SHIFT], 1);
  }
  __syncthreads();
  const int nC = gridDim.x;
  for (int b = t; b < EBINS; b += 256) echunkcnt[b * nC + blockIdx.x] = ebc[b];
  for (int b = t; b < NBINS; b += 256) nchunkcnt[b * nC + blockIdx.x] = nbc[b];
}

// Fused: bin totals -> exclusive bin bases -> per-(bin,chunk) run offsets.
// Block 0 handles edges, block 1 handles nodes.
__global__ __launch_bounds__(1024) void binscan_kernel(
    const int* __restrict__ echunkcnt, const int* __restrict__ nchunkcnt,
    int* __restrict__ erunoff, int* __restrict__ nrunoff,
    int* __restrict__ ebinbase, int* __restrict__ nbinbase, int nC) {
  __shared__ int s[512];
  const int t = threadIdx.x;
  const int* cc; int* ro; int* bb; int nb;
  if (blockIdx.x == 0) { cc = echunkcnt; ro = erunoff; bb = ebinbase; nb = EBINS; }
  else                 { cc = nchunkcnt; ro = nrunoff; bb = nbinbase; nb = NBINS; }
  int sum = 0;
  if (t < nb) for (int c = 0; c < nC; ++c) sum += cc[t * nC + c];
  if (t < 512) s[t] = (t < nb) ? sum : 0;
  __syncthreads();
  for (int d = 1; d < 512; d <<= 1) {
    int x = 0;
    if (t < 512 && t >= d) x = s[t - d];
    __syncthreads();
    if (t < 512) s[t] += x;
    __syncthreads();
  }
  if (t < nb) {
    int run = (t > 0) ? s[t - 1] : 0;
    bb[t] = run;
    for (int c = 0; c < nC; ++c) { ro[t * nC + c] = run; run += cc[t * nC + c]; }
  }
  if (t == 0) bb[nb] = s[nb - 1];
}

// Stage pass: each chunk writes its pairs into contiguous per-(bin,chunk) runs.
// LDS cursors only -- no global atomics, writes are localized contiguous runs.
__global__ __launch_bounds__(256) void stage_kernel(
    const int* __restrict__ node_idx, const int* __restrict__ edge_idx,
    const int* __restrict__ erunoff, const int* __restrict__ nrunoff,
    int2* __restrict__ epairs, int2* __restrict__ npairs, int nnz) {
  __shared__ int ecur[EBINS], ncur[NBINS];
  const int t = threadIdx.x;
  const int nC = gridDim.x;
  for (int b = t; b < EBINS; b += 256) ecur[b] = erunoff[b * nC + blockIdx.x];
  for (int b = t; b < NBINS; b += 256) ncur[b] = nrunoff[b * nC + blockIdx.x];
  __syncthreads();
  const int base = blockIdx.x * CHUNK;
  int end = base + CHUNK; if (end > nnz) end = nnz;
  for (int i = base + t; i < end; i += 256) {
    int e = edge_idx[i];
    int n = node_idx[i];
    int p = atomicAdd(&ecur[e >> EBIN_SHIFT], 1);
    epairs[p] = make_int2(e, n);
    int q = atomicAdd(&ncur[n >> NBIN_SHIFT], 1);
    npairs[q] = make_int2(n, e);
  }
}

// Final scatter: one block per bin. LDS histogram -> LDS exclusive scan gives
// per-segment CSR offsets (written to eoff/noff) AND scatter cursors.
__global__ __launch_bounds__(256) void bin_scatter_kernel(
    const int2* __restrict__ epairs, const int2* __restrict__ npairs,
    const int* __restrict__ ebinbase, const int* __restrict__ nbinbase,
    int* __restrict__ eoff, int* __restrict__ noff,
    int* __restrict__ enbr, int* __restrict__ nnbr,
    int n_edges, int n_nodes) {
  __shared__ int cnt[256];
  __shared__ int scn[256];
  const int bid = blockIdx.x;
  const int t = threadIdx.x;
  if (bid < EBINS) {
    const int e0 = bid << EBIN_SHIFT;
    const int ne = min(1 << EBIN_SHIFT, n_edges - e0);
    const int beg = ebinbase[bid], end = ebinbase[bid + 1];
    if (t < 128) cnt[t] = 0;
    __syncthreads();
    for (int j = beg + t; j < end; j += 256) atomicAdd(&cnt[epairs[j].x & 127], 1);
    __syncthreads();
    if (t < 128) scn[t] = cnt[t];
    __syncthreads();
    for (int d = 1; d < 128; d <<= 1) {
      int x = 0;
      if (t < 128 && t >= d) x = scn[t - d];
      __syncthreads();
      if (t < 128) scn[t] += x;
      __syncthreads();
    }
    int pos0 = 0;
    if (t < 128) {
      int excl = (t > 0) ? scn[t - 1] : 0;
      pos0 = beg + excl;
      if (t < ne) eoff[e0 + t] = pos0;
    }
    __syncthreads();
    if (t < 128) scn[t] = pos0;   // scatter cursors
    __syncthreads();
    for (int j = beg + t; j < end; j += 256) {
      int2 p = epairs[j];
      int pos = atomicAdd(&scn[p.x & 127], 1);
      enbr[pos] = p.y;
    }
    if (bid == EBINS - 1 && t == 0) eoff[n_edges] = end;
  } else {
    const int b = bid - EBINS;
    const int n0 = b << NBIN_SHIFT;
    const int nn = min(1 << NBIN_SHIFT, n_nodes - n0);
    const int beg = nbinbase[b], end = nbinbase[b + 1];
    cnt[t] = 0;
    __syncthreads();
    for (int j = beg + t; j < end; j += 256) atomicAdd(&cnt[npairs[j].x & 255], 1);
    __syncthreads();
    scn[t] = cnt[t];
    __syncthreads();
    for (int d = 1; d < 256; d <<= 1) {
      int x = (t >= d) ? scn[t - d] : 0;
      __syncthreads();
      scn[t] += x;
      __syncthreads();
    }
    int excl = (t > 0) ? scn[t - 1] : 0;
    int pos0 = beg + excl;
    if (t < nn) noff[n0 + t] = pos0;
    __syncthreads();
    scn[t] = pos0;
    __syncthreads();
    for (int j = beg + t; j < end; j += 256) {
      int2 p = npairs[j];
      int pos = atomicAdd(&scn[p.x & 255], 1);
      nnbr[pos] = p.y;
    }
    if (bid == EBINS + NBINS - 1 && t == 0) noff[n_nodes] = end;
  }
}

// ---------------- GEMM1: xw16[M x 128] = x[M x 128] @ W[128 x 128], fp16 out ----------------

__global__ __launch_bounds__(256) void gemm1_kernel(
    const float* __restrict__ A, const float* __restrict__ B,
    __half* __restrict__ C16, int M) {
  __shared__ float xs[128][36];
  __shared__ float wsh[32][128];

  const int t = threadIdx.x;
  const int tx = t & 15;
  const int ty = t >> 4;
  const int bm = blockIdx.x * 128;

  float acc[8][8];
#pragma unroll
  for (int i = 0; i < 8; ++i)
#pragma unroll
    for (int j = 0; j < 8; ++j) acc[i][j] = 0.f;

  for (int kt = 0; kt < 4; ++kt) {
#pragma unroll
    for (int i = 0; i < 4; ++i) {
      int lin = i * 256 + t;
      int row = lin >> 3;
      int c4 = lin & 7;
      int grow = bm + row;
      float4 v = make_float4(0.f, 0.f, 0.f, 0.f);
      if (grow < M) v = *(const float4*)(A + (size_t)grow * 128 + kt * 32 + c4 * 4);
      *(float4*)&xs[row][c4 * 4] = v;
    }
#pragma unroll
    for (int i = 0; i < 4; ++i) {
      int lin = i * 256 + t;
      int k = lin >> 5;
      int c4 = lin & 31;
      *(float4*)&wsh[k][c4 * 4] = *(const float4*)(B + (size_t)(kt * 32 + k) * 128 + c4 * 4);
    }
    __syncthreads();

#pragma unroll 4
    for (int k = 0; k < 32; ++k) {
      float a[8], b[8];
#pragma unroll
      for (int j = 0; j < 4; ++j) {
        a[j]     = xs[ty * 4 + j][k];
        a[4 + j] = xs[ty * 4 + 64 + j][k];
      }
      float4 b0 = *(const float4*)&wsh[k][tx * 4];
      float4 b1 = *(const float4*)&wsh[k][tx * 4 + 64];
      b[0] = b0.x; b[1] = b0.y; b[2] = b0.z; b[3] = b0.w;
      b[4] = b1.x; b[5] = b1.y; b[6] = b1.z; b[7] = b1.w;
#pragma unroll
      for (int i = 0; i < 8; ++i)
#pragma unroll
        for (int j = 0; j < 8; ++j) acc[i][j] = fmaf(a[i], b[j], acc[i][j]);
    }
    __syncthreads();
  }

#pragma unroll
  for (int i = 0; i < 8; ++i) {
    int row = (i < 4) ? (ty * 4 + i) : (ty * 4 + 64 + (i - 4));
    int grow = bm + row;
    if (grow < M) {
      __half2* rp = (__half2*)(C16 + (size_t)grow * 128);
      rp[tx * 2]      = __floats2half2_rn(acc[i][0], acc[i][1]);
      rp[tx * 2 + 1]  = __floats2half2_rn(acc[i][2], acc[i][3]);
      rp[32 + tx * 2]     = __floats2half2_rn(acc[i][4], acc[i][5]);
      rp[32 + tx * 2 + 1] = __floats2half2_rn(acc[i][6], acc[i][7]);
    }
  }
}

// ---------------- Segment aggregation, F=128 fp16 (one wave per segment) ----------------

__global__ __launch_bounds__(256) void edge_agg128_kernel(
    const __half2* __restrict__ feat, const int* __restrict__ nbr,
    const int* __restrict__ off, __half2* __restrict__ outf, int nseg) {
  int w = (blockIdx.x * 256 + threadIdx.x) >> 6;
  int lane = threadIdx.x & 63;
  if (w >= nseg) return;
  int beg = off[w], end = off[w + 1];
  float ax = 0.f, ay = 0.f, bx = 0.f, by = 0.f;
  int j = beg;
  for (; j + 2 <= end; j += 2) {
    int n0 = nbr[j], n1 = nbr[j + 1];
    float2 v0 = __half22float2(feat[(size_t)n0 * 64 + lane]);
    float2 v1 = __half22float2(feat[(size_t)n1 * 64 + lane]);
    ax += v0.x; ay += v0.y; bx += v1.x; by += v1.y;
  }
  if (j < end) {
    float2 v = __half22float2(feat[(size_t)nbr[j] * 64 + lane]);
    ax += v.x; ay += v.y;
  }
  float inv = (end > beg) ? 1.f / (float)(end - beg) : 0.f;
  outf[(size_t)w * 64 + lane] = __floats2half2_rn((ax + bx) * inv, (ay + by) * inv);
}

__global__ __launch_bounds__(256) void node_agg128_kernel(
    const __half2* __restrict__ feat, const int* __restrict__ nbr,
    const int* __restrict__ off, const float* __restrict__ bias,
    __half2* __restrict__ outf, int nseg) {
  int w = (blockIdx.x * 256 + threadIdx.x) >> 6;
  int lane = threadIdx.x & 63;
  if (w >= nseg) return;
  int beg = off[w], end = off[w + 1];
  float ax = 0.f, ay = 0.f, bx = 0.f, by = 0.f;
  int j = beg;
  for (; j + 2 <= end; j += 2) {
    int e0 = nbr[j], e1 = nbr[j + 1];
    float2 v0 = __half22float2(feat[(size_t)e0 * 64 + lane]);
    float2 v1 = __half22float2(feat[(size_t)e1 * 64 + lane]);
    ax += v0.x; ay += v0.y; bx += v1.x; by += v1.y;
  }
  if (j < end) {
    float2 v = __half22float2(feat[(size_t)nbr[j] * 64 + lane]);
    ax += v.x; ay += v.y;
  }
  float inv = (end > beg) ? 1.f / (float)(end - beg) : 0.f;
  float2 b = *(const float2*)(bias + lane * 2);
  float hx = fmaxf((ax + bx) * inv + b.x, 0.f);   // + b1, ReLU
  float hy = fmaxf((ay + by) * inv + b.y, 0.f);
  outf[(size_t)w * 64 + lane] = __floats2half2_rn(hx, hy);
}

// ---------------- GEMM2: hw2[M x 16] = h16[M x 128] @ W2[128 x 16] ----------------

__global__ __launch_bounds__(256) void gemm2_kernel(
    const __half* __restrict__ H16, const float* __restrict__ W2,
    float* __restrict__ O, int M) {
  __shared__ float ws2[128 * 16];
  const int t = threadIdx.x;
#pragma unroll
  for (int i = 0; i < 8; ++i) ws2[i * 256 + t] = W2[i * 256 + t];
  __syncthreads();

  int r0 = blockIdx.x * 512 + t;
  int r1 = r0 + 256;
  bool v0 = r0 < M, v1 = r1 < M;
  const __half2* h0 = (const __half2*)(H16 + (size_t)r0 * 128);
  const __half2* h1 = (const __half2*)(H16 + (size_t)r1 * 128);

  float4 acc0[4], acc1[4];
#pragma unroll
  for (int q = 0; q < 4; ++q) {
    acc0[q] = make_float4(0.f, 0.f, 0.f, 0.f);
    acc1[q] = make_float4(0.f, 0.f, 0.f, 0.f);
  }

  for (int k4 = 0; k4 < 32; ++k4) {
    float2 f00 = make_float2(0.f, 0.f), f01 = make_float2(0.f, 0.f);
    float2 f10 = make_float2(0.f, 0.f), f11 = make_float2(0.f, 0.f);
    if (v0) { f00 = __half22float2(h0[2 * k4]); f01 = __half22float2(h0[2 * k4 + 1]); }
    if (v1) { f10 = __half22float2(h1[2 * k4]); f11 = __half22float2(h1[2 * k4 + 1]); }
    const float a0s[4] = {f00.x, f00.y, f01.x, f01.y};
    const float a1s[4] = {f10.x, f10.y, f11.x, f11.y};
#pragma unroll
    for (int j = 0; j < 4; ++j) {
      int k = k4 * 4 + j;
#pragma unroll
      for (int q = 0; q < 4; ++q) {
        float4 b = *(const float4*)&ws2[k * 16 + q * 4];
        acc0[q].x = fmaf(a0s[j], b.x, acc0[q].x);
        acc0[q].y = fmaf(a0s[j], b.y, acc0[q].y);
        acc0[q].z = fmaf(a0s[j], b.z, acc0[q].z);
        acc0[q].w = fmaf(a0s[j], b.w, acc0[q].w);
        acc1[q].x = fmaf(a1s[j], b.x, acc1[q].x);
        acc1[q].y = fmaf(a1s[j], b.y, acc1[q].y);
        acc1[q].z = fmaf(a1s[j], b.z, acc1[q].z);
        acc1[q].w = fmaf(a1s[j], b.w, acc1[q].w);
      }
    }
  }
  if (v0) {
#pragma unroll
    for (int q = 0; q < 4; ++q) *(float4*)(O + (size_t)r0 * 16 + q * 4) = acc0[q];
  }
  if (v1) {
#pragma unroll
    for (int q = 0; q < 4; ++q) *(float4*)(O + (size_t)r1 * 16 + q * 4) = acc1[q];
  }
}

// ---------------- Segment aggregation, F=16 (fp32) ----------------

__global__ __launch_bounds__(256) void edge_agg16_kernel(
    const float* __restrict__ feat, const int* __restrict__ nbr,
    const int* __restrict__ off, float* __restrict__ outf, int nseg) {
  int gid = blockIdx.x * 256 + threadIdx.x;
  int seg = gid >> 4;
  int c = gid & 15;
  if (seg >= nseg) return;
  int beg = off[seg], end = off[seg + 1];
  float acc = 0.f;
  for (int j = beg; j < end; ++j) acc += feat[(size_t)nbr[j] * 16 + c];
  float inv = (end > beg) ? 1.f / (float)(end - beg) : 0.f;
  outf[(size_t)seg * 16 + c] = acc * inv;
}

__global__ __launch_bounds__(256) void node_agg16_kernel(
    const float* __restrict__ feat, const int* __restrict__ nbr,
    const int* __restrict__ off, const float* __restrict__ bias,
    float* __restrict__ outf, int nseg) {
  int gid = blockIdx.x * 256 + threadIdx.x;
  int seg = gid >> 4;
  int c = gid & 15;
  if (seg >= nseg) return;
  int beg = off[seg], end = off[seg + 1];
  float acc = 0.f;
  for (int j = beg; j < end; ++j) acc += feat[(size_t)nbr[j] * 16 + c];
  float inv = (end > beg) ? 1.f / (float)(end - beg) : 0.f;
  outf[(size_t)seg * 16 + c] = acc * inv + bias[c];
}

// ---------------- launch ----------------

extern "C" void kernel_launch(void* const* d_in, const int* in_sizes, int n_in,
                              void* d_out, int out_size, void* d_ws, size_t ws_size,
                              hipStream_t stream) {
  const float* x        = (const float*)d_in[0];
  const int*   node_idx = (const int*)d_in[1];
  const int*   edge_idx = (const int*)d_in[2];
  const float* W1 = (const float*)d_in[4];
  const float* b1 = (const float*)d_in[5];
  const float* W2 = (const float*)d_in[6];
  const float* b2 = (const float*)d_in[7];
  float* out = (float*)d_out;

  const int n_nodes = in_sizes[0] / F1;  // 100000
  const int nnz     = in_sizes[1];       // 1600000
  const int n_edges = N_EDGES_C;         // 50000
  const int nC      = (nnz + CHUNK - 1) / CHUNK;   // 391

  char* ws = (char*)d_ws;
  // layout (bytes), high-water ~89.5 MB (97.4 MB known-safe from R1):
  int2*   epairs = (int2*)(ws + 0);            // 12.8M transient (consumed by bin_scatter)
  int2*   npairs = (int2*)(ws + 12800000);     // 12.8M transient
  __half* h16    = (__half*)(ws + 0);          // 25.6M (written by nagg128, after bin_scatter)
  __half* xw16   = (__half*)(ws + 25600000);   // 25.6M
  __half* ef16   = (__half*)(ws + 51200000);   // 12.8M
  float*  hw2    = (float*)(ws + 64000000);    //  6.4M
  float*  ef2    = (float*)(ws + 70400000);    //  3.2M
  int*    enbr   = (int*)(ws + 73600000);      //  6.4M
  int*    nnbr   = (int*)(ws + 80000000);      //  6.4M
  int*    eoff   = (int*)(ws + 86400000);      //  200,004
  int*    noff   = (int*)(ws + 86600008);      //  400,004
  int*    echunkcnt = (int*)(ws + 87000016);   //  611,524 (EBINS*nC)
  int*    nchunkcnt = (int*)(ws + 87611540);   //  611,524
  int*    erunoff   = (int*)(ws + 88223064);   //  611,524
  int*    nrunoff   = (int*)(ws + 88834588);   //  611,524
  int*    ebinbase  = (int*)(ws + 89446112);   //  1,568 (392 ints)
  int*    nbinbase  = (int*)(ws + 89447680);   //  1,568 -> end 89,449,248

  // No memset needed: every buffer is fully written before it is read.

  hist_chunk_kernel<<<nC, 256, 0, stream>>>(node_idx, edge_idx,
                                            echunkcnt, nchunkcnt, nnz);
  binscan_kernel<<<2, 1024, 0, stream>>>(echunkcnt, nchunkcnt, erunoff, nrunoff,
                                         ebinbase, nbinbase, nC);
  stage_kernel<<<nC, 256, 0, stream>>>(node_idx, edge_idx, erunoff, nrunoff,
                                       epairs, npairs, nnz);
  bin_scatter_kernel<<<EBINS + NBINS, 256, 0, stream>>>(epairs, npairs,
                                                        ebinbase, nbinbase,
                                                        eoff, noff, enbr, nnbr,
                                                        n_edges, n_nodes);

  // layer 1 (fp16 message path)
  gemm1_kernel<<<(n_nodes + 127) / 128, 256, 0, stream>>>(x, W1, xw16, n_nodes);
  edge_agg128_kernel<<<(n_edges * 64 + 255) / 256, 256, 0, stream>>>(
      (const __half2*)xw16, enbr, eoff, (__half2*)ef16, n_edges);
  node_agg128_kernel<<<(n_nodes * 64 + 255) / 256, 256, 0, stream>>>(
      (const __half2*)ef16, nnbr, noff, b1, (__half2*)h16, n_nodes);

  // layer 2
  gemm2_kernel<<<(n_nodes + 511) / 512, 256, 0, stream>>>(h16, W2, hw2, n_nodes);
  edge_agg16_kernel<<<(n_edges * 16 + 255) / 256, 256, 0, stream>>>(hw2, enbr, eoff, ef2, n_edges);
  node_agg16_kernel<<<(n_nodes * 16 + 255) / 256, 256, 0, stream>>>(ef2, nnbr, noff, b2, out, n_nodes);
}

// Round 7
// 515.467 us; speedup vs baseline: 2.2284x; 1.4484x over previous
//
#include <hip/hip_runtime.h>
#include <hip/hip_fp16.h>

// Problem constants: N_NODES=100000, N_EDGES=50000, NNZ=1600000, dims 128->128->16, fp32 I/O.
// Internal message path (xw, e_feat, h) stored fp16, accumulated fp32.
// CSR build: counting sort with NO global atomics anywhere (LDS histograms only).

#define N_EDGES_C 50000
#define F1 128
#define F2 16
#define CHUNK 4096                // elements per chunk (391 chunks -> good occupancy)
#define EBIN_SHIFT 7              // 128 edges per bin
#define NBIN_SHIFT 8              // 256 nodes per bin
#define EBINS 391                 // ceil(50000/128)
#define NBINS 391                 // ceil(100000/256)

// ---------------- CSR build ----------------

// Per-(chunk,bin) counts via LDS histograms. No global atomics.
__global__ __launch_bounds__(256) void hist_chunk_kernel(
    const int* __restrict__ node_idx, const int* __restrict__ edge_idx,
    int* __restrict__ echunkcnt, int* __restrict__ nchunkcnt, int nnz) {
  __shared__ int ebc[EBINS], nbc[NBINS];
  const int t = threadIdx.x;
  for (int b = t; b < EBINS; b += 256) ebc[b] = 0;
  for (int b = t; b < NBINS; b += 256) nbc[b] = 0;
  __syncthreads();
  const int base = blockIdx.x * CHUNK;
  int end = base + CHUNK; if (end > nnz) end = nnz;
  for (int i = base + t; i < end; i += 256) {
    atomicAdd(&ebc[edge_idx[i] >> EBIN_SHIFT], 1);
    atomicAdd(&nbc[node_idx[i] >> NBIN_SHIFT], 1);
  }
  __syncthreads();
  const int nC = gridDim.x;
  for (int b = t; b < EBINS; b += 256) echunkcnt[b * nC + blockIdx.x] = ebc[b];
  for (int b = t; b < NBINS; b += 256) nchunkcnt[b * nC + blockIdx.x] = nbc[b];
}

// ---- runoff = exclusive prefix sum over flattened bin-major chunk counts ----
// (erunoff[b*nC+c] = sum of all earlier (bin,chunk) counts; ebinbase[b] =
//  erunoff[b*nC]; sentinel binbase[last] = nnz.)  3-phase hierarchical scan,
//  1024 elements per block, both arrays in one grid.

__global__ __launch_bounds__(256) void cscan_p1_kernel(
    const int* __restrict__ ecc, const int* __restrict__ ncc,
    int* __restrict__ epart, int* __restrict__ npart,
    int Le, int Ln, int nbE) {
  __shared__ int red[256];
  const int t = threadIdx.x;
  const int b = blockIdx.x;
  const int* src; int L; int* dst; int bb;
  if (b < nbE) { src = ecc; L = Le; dst = epart; bb = b; }
  else         { src = ncc; L = Ln; dst = npart; bb = b - nbE; }
  int base = bb * 1024 + t * 4;
  int s = 0;
#pragma unroll
  for (int j = 0; j < 4; ++j) { int i = base + j; if (i < L) s += src[i]; }
  red[t] = s;
  __syncthreads();
  for (int d = 128; d > 0; d >>= 1) {
    if (t < d) red[t] += red[t + d];
    __syncthreads();
  }
  if (t == 0) dst[bb] = red[0];
}

__global__ __launch_bounds__(256) void cscan_p2_kernel(
    int* __restrict__ epart, int* __restrict__ npart,
    int* __restrict__ ebinbase, int* __restrict__ nbinbase,
    int nbE, int nbN, int nnz) {
  __shared__ int se[256], sn[256];
  const int t = threadIdx.x;
  se[t] = (t < nbE) ? epart[t] : 0;
  sn[t] = (t < nbN) ? npart[t] : 0;
  __syncthreads();
  for (int d = 1; d < 256; d <<= 1) {
    int ve = (t >= d) ? se[t - d] : 0;
    int vn = (t >= d) ? sn[t - d] : 0;
    __syncthreads();
    se[t] += ve; sn[t] += vn;
    __syncthreads();
  }
  if (t < nbE) epart[t] = (t > 0) ? se[t - 1] : 0;
  if (t < nbN) npart[t] = (t > 0) ? sn[t - 1] : 0;
  if (t == 0) { ebinbase[EBINS] = nnz; nbinbase[NBINS] = nnz; }
}

__global__ __launch_bounds__(256) void cscan_p3_kernel(
    const int* __restrict__ ecc, const int* __restrict__ ncc,
    const int* __restrict__ epart, const int* __restrict__ npart,
    int* __restrict__ erunoff, int* __restrict__ nrunoff,
    int* __restrict__ ebinbase, int* __restrict__ nbinbase,
    int Le, int Ln, int nbE, int nC) {
  __shared__ int red[256];
  const int t = threadIdx.x;
  const int b = blockIdx.x;
  const int* src; const int* part; int L; int* ro; int* bba; int bb;
  if (b < nbE) { src = ecc; part = epart; L = Le; ro = erunoff; bba = ebinbase; bb = b; }
  else         { src = ncc; part = npart; L = Ln; ro = nrunoff; bba = nbinbase; bb = b - nbE; }
  int base = bb * 1024 + t * 4;
  int v[4]; int s = 0;
#pragma unroll
  for (int j = 0; j < 4; ++j) { int i = base + j; v[j] = (i < L) ? src[i] : 0; s += v[j]; }
  red[t] = s;
  __syncthreads();
  for (int d = 1; d < 256; d <<= 1) {
    int x = (t >= d) ? red[t - d] : 0;
    __syncthreads();
    red[t] += x;
    __syncthreads();
  }
  int run = part[bb] + ((t > 0) ? red[t - 1] : 0);
#pragma unroll
  for (int j = 0; j < 4; ++j) {
    int i = base + j;
    if (i < L) {
      ro[i] = run;
      if (i % nC == 0) bba[i / nC] = run;
      run += v[j];
    }
  }
}

// Stage pass: each chunk writes its pairs into contiguous per-(bin,chunk) runs.
// LDS cursors only -- no global atomics, writes are localized contiguous runs.
__global__ __launch_bounds__(256) void stage_kernel(
    const int* __restrict__ node_idx, const int* __restrict__ edge_idx,
    const int* __restrict__ erunoff, const int* __restrict__ nrunoff,
    int2* __restrict__ epairs, int2* __restrict__ npairs, int nnz) {
  __shared__ int ecur[EBINS], ncur[NBINS];
  const int t = threadIdx.x;
  const int nC = gridDim.x;
  for (int b = t; b < EBINS; b += 256) ecur[b] = erunoff[b * nC + blockIdx.x];
  for (int b = t; b < NBINS; b += 256) ncur[b] = nrunoff[b * nC + blockIdx.x];
  __syncthreads();
  const int base = blockIdx.x * CHUNK;
  int end = base + CHUNK; if (end > nnz) end = nnz;
  for (int i = base + t; i < end; i += 256) {
    int e = edge_idx[i];
    int n = node_idx[i];
    int p = atomicAdd(&ecur[e >> EBIN_SHIFT], 1);
    epairs[p] = make_int2(e, n);
    int q = atomicAdd(&ncur[n >> NBIN_SHIFT], 1);
    npairs[q] = make_int2(n, e);
  }
}

// Final scatter: one block per bin. LDS histogram -> LDS exclusive scan gives
// per-segment CSR offsets (written to eoff/noff) AND scatter cursors.
__global__ __launch_bounds__(256) void bin_scatter_kernel(
    const int2* __restrict__ epairs, const int2* __restrict__ npairs,
    const int* __restrict__ ebinbase, const int* __restrict__ nbinbase,
    int* __restrict__ eoff, int* __restrict__ noff,
    int* __restrict__ enbr, int* __restrict__ nnbr,
    int n_edges, int n_nodes) {
  __shared__ int cnt[256];
  __shared__ int scn[256];
  const int bid = blockIdx.x;
  const int t = threadIdx.x;
  if (bid < EBINS) {
    const int e0 = bid << EBIN_SHIFT;
    const int ne = min(1 << EBIN_SHIFT, n_edges - e0);
    const int beg = ebinbase[bid], end = ebinbase[bid + 1];
    if (t < 128) cnt[t] = 0;
    __syncthreads();
    for (int j = beg + t; j < end; j += 256) atomicAdd(&cnt[epairs[j].x & 127], 1);
    __syncthreads();
    if (t < 128) scn[t] = cnt[t];
    __syncthreads();
    for (int d = 1; d < 128; d <<= 1) {
      int x = 0;
      if (t < 128 && t >= d) x = scn[t - d];
      __syncthreads();
      if (t < 128) scn[t] += x;
      __syncthreads();
    }
    int pos0 = 0;
    if (t < 128) {
      int excl = (t > 0) ? scn[t - 1] : 0;
      pos0 = beg + excl;
      if (t < ne) eoff[e0 + t] = pos0;
    }
    __syncthreads();
    if (t < 128) scn[t] = pos0;   // scatter cursors
    __syncthreads();
    for (int j = beg + t; j < end; j += 256) {
      int2 p = epairs[j];
      int pos = atomicAdd(&scn[p.x & 127], 1);
      enbr[pos] = p.y;
    }
    if (bid == EBINS - 1 && t == 0) eoff[n_edges] = end;
  } else {
    const int b = bid - EBINS;
    const int n0 = b << NBIN_SHIFT;
    const int nn = min(1 << NBIN_SHIFT, n_nodes - n0);
    const int beg = nbinbase[b], end = nbinbase[b + 1];
    cnt[t] = 0;
    __syncthreads();
    for (int j = beg + t; j < end; j += 256) atomicAdd(&cnt[npairs[j].x & 255], 1);
    __syncthreads();
    scn[t] = cnt[t];
    __syncthreads();
    for (int d = 1; d < 256; d <<= 1) {
      int x = (t >= d) ? scn[t - d] : 0;
      __syncthreads();
      scn[t] += x;
      __syncthreads();
    }
    int excl = (t > 0) ? scn[t - 1] : 0;
    int pos0 = beg + excl;
    if (t < nn) noff[n0 + t] = pos0;
    __syncthreads();
    scn[t] = pos0;
    __syncthreads();
    for (int j = beg + t; j < end; j += 256) {
      int2 p = npairs[j];
      int pos = atomicAdd(&scn[p.x & 255], 1);
      nnbr[pos] = p.y;
    }
    if (bid == EBINS + NBINS - 1 && t == 0) noff[n_nodes] = end;
  }
}

// ---------------- GEMM1: xw16[M x 128] = x[M x 128] @ W[128 x 128], fp16 out ----------------

__global__ __launch_bounds__(256) void gemm1_kernel(
    const float* __restrict__ A, const float* __restrict__ B,
    __half* __restrict__ C16, int M) {
  __shared__ float xs[128][36];
  __shared__ float wsh[32][128];

  const int t = threadIdx.x;
  const int tx = t & 15;
  const int ty = t >> 4;
  const int bm = blockIdx.x * 128;

  float acc[8][8];
#pragma unroll
  for (int i = 0; i < 8; ++i)
#pragma unroll
    for (int j = 0; j < 8; ++j) acc[i][j] = 0.f;

  for (int kt = 0; kt < 4; ++kt) {
#pragma unroll
    for (int i = 0; i < 4; ++i) {
      int lin = i * 256 + t;
      int row = lin >> 3;
      int c4 = lin & 7;
      int grow = bm + row;
      float4 v = make_float4(0.f, 0.f, 0.f, 0.f);
      if (grow < M) v = *(const float4*)(A + (size_t)grow * 128 + kt * 32 + c4 * 4);
      *(float4*)&xs[row][c4 * 4] = v;
    }
#pragma unroll
    for (int i = 0; i < 4; ++i) {
      int lin = i * 256 + t;
      int k = lin >> 5;
      int c4 = lin & 31;
      *(float4*)&wsh[k][c4 * 4] = *(const float4*)(B + (size_t)(kt * 32 + k) * 128 + c4 * 4);
    }
    __syncthreads();

#pragma unroll 4
    for (int k = 0; k < 32; ++k) {
      float a[8], b[8];
#pragma unroll
      for (int j = 0; j < 4; ++j) {
        a[j]     = xs[ty * 4 + j][k];
        a[4 + j] = xs[ty * 4 + 64 + j][k];
      }
      float4 b0 = *(const float4*)&wsh[k][tx * 4];
      float4 b1 = *(const float4*)&wsh[k][tx * 4 + 64];
      b[0] = b0.x; b[1] = b0.y; b[2] = b0.z; b[3] = b0.w;
      b[4] = b1.x; b[5] = b1.y; b[6] = b1.z; b[7] = b1.w;
#pragma unroll
      for (int i = 0; i < 8; ++i)
#pragma unroll
        for (int j = 0; j < 8; ++j) acc[i][j] = fmaf(a[i], b[j], acc[i][j]);
    }
    __syncthreads();
  }

#pragma unroll
  for (int i = 0; i < 8; ++i) {
    int row = (i < 4) ? (ty * 4 + i) : (ty * 4 + 64 + (i - 4));
    int grow = bm + row;
    if (grow < M) {
      __half2* rp = (__half2*)(C16 + (size_t)grow * 128);
      rp[tx * 2]      = __floats2half2_rn(acc[i][0], acc[i][1]);
      rp[tx * 2 + 1]  = __floats2half2_rn(acc[i][2], acc[i][3]);
      rp[32 + tx * 2]     = __floats2half2_rn(acc[i][4], acc[i][5]);
      rp[32 + tx * 2 + 1] = __floats2half2_rn(acc[i][6], acc[i][7]);
    }
  }
}

// ---------------- Segment aggregation, F=128 fp16 (one wave per segment) ----------------

__global__ __launch_bounds__(256) void edge_agg128_kernel(
    const __half2* __restrict__ feat, const int* __restrict__ nbr,
    const int* __restrict__ off, __half2* __restrict__ outf, int nseg) {
  int w = (blockIdx.x * 256 + threadIdx.x) >> 6;
  int lane = threadIdx.x & 63;
  if (w >= nseg) return;
  int beg = off[w], end = off[w + 1];
  float ax = 0.f, ay = 0.f, bx = 0.f, by = 0.f;
  int j = beg;
  for (; j + 2 <= end; j += 2) {
    int n0 = nbr[j], n1 = nbr[j + 1];
    float2 v0 = __half22float2(feat[(size_t)n0 * 64 + lane]);
    float2 v1 = __half22float2(feat[(size_t)n1 * 64 + lane]);
    ax += v0.x; ay += v0.y; bx += v1.x; by += v1.y;
  }
  if (j < end) {
    float2 v = __half22float2(feat[(size_t)nbr[j] * 64 + lane]);
    ax += v.x; ay += v.y;
  }
  float inv = (end > beg) ? 1.f / (float)(end - beg) : 0.f;
  outf[(size_t)w * 64 + lane] = __floats2half2_rn((ax + bx) * inv, (ay + by) * inv);
}

__global__ __launch_bounds__(256) void node_agg128_kernel(
    const __half2* __restrict__ feat, const int* __restrict__ nbr,
    const int* __restrict__ off, const float* __restrict__ bias,
    __half2* __restrict__ outf, int nseg) {
  int w = (blockIdx.x * 256 + threadIdx.x) >> 6;
  int lane = threadIdx.x & 63;
  if (w >= nseg) return;
  int beg = off[w], end = off[w + 1];
  float ax = 0.f, ay = 0.f, bx = 0.f, by = 0.f;
  int j = beg;
  for (; j + 2 <= end; j += 2) {
    int e0 = nbr[j], e1 = nbr[j + 1];
    float2 v0 = __half22float2(feat[(size_t)e0 * 64 + lane]);
    float2 v1 = __half22float2(feat[(size_t)e1 * 64 + lane]);
    ax += v0.x; ay += v0.y; bx += v1.x; by += v1.y;
  }
  if (j < end) {
    float2 v = __half22float2(feat[(size_t)nbr[j] * 64 + lane]);
    ax += v.x; ay += v.y;
  }
  float inv = (end > beg) ? 1.f / (float)(end - beg) : 0.f;
  float2 b = *(const float2*)(bias + lane * 2);
  float hx = fmaxf((ax + bx) * inv + b.x, 0.f);   // + b1, ReLU
  float hy = fmaxf((ay + by) * inv + b.y, 0.f);
  outf[(size_t)w * 64 + lane] = __floats2half2_rn(hx, hy);
}

// ---------------- GEMM2: hw2[M x 16] = h16[M x 128] @ W2[128 x 16] ----------------

__global__ __launch_bounds__(256) void gemm2_kernel(
    const __half* __restrict__ H16, const float* __restrict__ W2,
    float* __restrict__ O, int M) {
  __shared__ float ws2[128 * 16];
  const int t = threadIdx.x;
#pragma unroll
  for (int i = 0; i < 8; ++i) ws2[i * 256 + t] = W2[i * 256 + t];
  __syncthreads();

  int r0 = blockIdx.x * 512 + t;
  int r1 = r0 + 256;
  bool v0 = r0 < M, v1 = r1 < M;
  const __half2* h0 = (const __half2*)(H16 + (size_t)r0 * 128);
  const __half2* h1 = (const __half2*)(H16 + (size_t)r1 * 128);

  float4 acc0[4], acc1[4];
#pragma unroll
  for (int q = 0; q < 4; ++q) {
    acc0[q] = make_float4(0.f, 0.f, 0.f, 0.f);
    acc1[q] = make_float4(0.f, 0.f, 0.f, 0.f);
  }

  for (int k4 = 0; k4 < 32; ++k4) {
    float2 f00 = make_float2(0.f, 0.f), f01 = make_float2(0.f, 0.f);
    float2 f10 = make_float2(0.f, 0.f), f11 = make_float2(0.f, 0.f);
    if (v0) { f00 = __half22float2(h0[2 * k4]); f01 = __half22float2(h0[2 * k4 + 1]); }
    if (v1) { f10 = __half22float2(h1[2 * k4]); f11 = __half22float2(h1[2 * k4 + 1]); }
    const float a0s[4] = {f00.x, f00.y, f01.x, f01.y};
    const float a1s[4] = {f10.x, f10.y, f11.x, f11.y};
#pragma unroll
    for (int j = 0; j < 4; ++j) {
      int k = k4 * 4 + j;
#pragma unroll
      for (int q = 0; q < 4; ++q) {
        float4 b = *(const float4*)&ws2[k * 16 + q * 4];
        acc0[q].x = fmaf(a0s[j], b.x, acc0[q].x);
        acc0[q].y = fmaf(a0s[j], b.y, acc0[q].y);
        acc0[q].z = fmaf(a0s[j], b.z, acc0[q].z);
        acc0[q].w = fmaf(a0s[j], b.w, acc0[q].w);
        acc1[q].x = fmaf(a1s[j], b.x, acc1[q].x);
        acc1[q].y = fmaf(a1s[j], b.y, acc1[q].y);
        acc1[q].z = fmaf(a1s[j], b.z, acc1[q].z);
        acc1[q].w = fmaf(a1s[j], b.w, acc1[q].w);
      }
    }
  }
  if (v0) {
#pragma unroll
    for (int q = 0; q < 4; ++q) *(float4*)(O + (size_t)r0 * 16 + q * 4) = acc0[q];
  }
  if (v1) {
#pragma unroll
    for (int q = 0; q < 4; ++q) *(float4*)(O + (size_t)r1 * 16 + q * 4) = acc1[q];
  }
}

// ---------------- Segment aggregation, F=16 (fp32) ----------------

__global__ __launch_bounds__(256) void edge_agg16_kernel(
    const float* __restrict__ feat, const int* __restrict__ nbr,
    const int* __restrict__ off, float* __restrict__ outf, int nseg) {
  int gid = blockIdx.x * 256 + threadIdx.x;
  int seg = gid >> 4;
  int c = gid & 15;
  if (seg >= nseg) return;
  int beg = off[seg], end = off[seg + 1];
  float acc = 0.f;
  for (int j = beg; j < end; ++j) acc += feat[(size_t)nbr[j] * 16 + c];
  float inv = (end > beg) ? 1.f / (float)(end - beg) : 0.f;
  outf[(size_t)seg * 16 + c] = acc * inv;
}

__global__ __launch_bounds__(256) void node_agg16_kernel(
    const float* __restrict__ feat, const int* __restrict__ nbr,
    const int* __restrict__ off, const float* __restrict__ bias,
    float* __restrict__ outf, int nseg) {
  int gid = blockIdx.x * 256 + threadIdx.x;
  int seg = gid >> 4;
  int c = gid & 15;
  if (seg >= nseg) return;
  int beg = off[seg], end = off[seg + 1];
  float acc = 0.f;
  for (int j = beg; j < end; ++j) acc += feat[(size_t)nbr[j] * 16 + c];
  float inv = (end > beg) ? 1.f / (float)(end - beg) : 0.f;
  outf[(size_t)seg * 16 + c] = acc * inv + bias[c];
}

// ---------------- launch ----------------

extern "C" void kernel_launch(void* const* d_in, const int* in_sizes, int n_in,
                              void* d_out, int out_size, void* d_ws, size_t ws_size,
                              hipStream_t stream) {
  const float* x        = (const float*)d_in[0];
  const int*   node_idx = (const int*)d_in[1];
  const int*   edge_idx = (const int*)d_in[2];
  const float* W1 = (const float*)d_in[4];
  const float* b1 = (const float*)d_in[5];
  const float* W2 = (const float*)d_in[6];
  const float* b2 = (const float*)d_in[7];
  float* out = (float*)d_out;

  const int n_nodes = in_sizes[0] / F1;  // 100000
  const int nnz     = in_sizes[1];       // 1600000
  const int n_edges = N_EDGES_C;         // 50000
  const int nC      = (nnz + CHUNK - 1) / CHUNK;   // 391
  const int Le      = EBINS * nC;                  // 152,881
  const int Ln      = NBINS * nC;
  const int nbE     = (Le + 1023) / 1024;          // 150
  const int nbN     = (Ln + 1023) / 1024;

  char* ws = (char*)d_ws;
  // layout (bytes), high-water ~89.5 MB (97.4 MB known-safe from R1):
  int2*   epairs = (int2*)(ws + 0);            // 12.8M transient (consumed by bin_scatter)
  int2*   npairs = (int2*)(ws + 12800000);     // 12.8M transient
  __half* h16    = (__half*)(ws + 0);          // 25.6M (written by nagg128, after bin_scatter)
  __half* xw16   = (__half*)(ws + 25600000);   // 25.6M
  __half* ef16   = (__half*)(ws + 51200000);   // 12.8M
  float*  hw2    = (float*)(ws + 64000000);    //  6.4M
  float*  ef2    = (float*)(ws + 70400000);    //  3.2M
  int*    enbr   = (int*)(ws + 73600000);      //  6.4M
  int*    nnbr   = (int*)(ws + 80000000);      //  6.4M
  int*    eoff   = (int*)(ws + 86400000);      //  200,004
  int*    noff   = (int*)(ws + 86600008);      //  400,004
  int*    echunkcnt = (int*)(ws + 87000016);   //  611,524 (EBINS*nC)
  int*    nchunkcnt = (int*)(ws + 87611540);   //  611,524
  int*    erunoff   = (int*)(ws + 88223064);   //  611,524
  int*    nrunoff   = (int*)(ws + 88834588);   //  611,524
  int*    ebinbase  = (int*)(ws + 89446112);   //  1,568 (392 ints)
  int*    nbinbase  = (int*)(ws + 89447680);   //  1,568
  int*    epart     = (int*)(ws + 89449248);   //  1,024 (256 ints)
  int*    npart     = (int*)(ws + 89450272);   //  1,024 -> end 89,451,296

  hist_chunk_kernel<<<nC, 256, 0, stream>>>(node_idx, edge_idx,
                                            echunkcnt, nchunkcnt, nnz);
  cscan_p1_kernel<<<nbE + nbN, 256, 0, stream>>>(echunkcnt, nchunkcnt,
                                                 epart, npart, Le, Ln, nbE);
  cscan_p2_kernel<<<1, 256, 0, stream>>>(epart, npart, ebinbase, nbinbase,
                                         nbE, nbN, nnz);
  cscan_p3_kernel<<<nbE + nbN, 256, 0, stream>>>(echunkcnt, nchunkcnt,
                                                 epart, npart, erunoff, nrunoff,
                                                 ebinbase, nbinbase, Le, Ln, nbE, nC);
  stage_kernel<<<nC, 256, 0, stream>>>(node_idx, edge_idx, erunoff, nrunoff,
                                       epairs, npairs, nnz);
  bin_scatter_kernel<<<EBINS + NBINS, 256, 0, stream>>>(epairs, npairs,
                                                        ebinbase, nbinbase,
                                                        eoff, noff, enbr, nnbr,
                                                        n_edges, n_nodes);

  // layer 1 (fp16 message path)
  gemm1_kernel<<<(n_nodes + 127) / 128, 256, 0, stream>>>(x, W1, xw16, n_nodes);
  edge_agg128_kernel<<<(n_edges * 64 + 255) / 256, 256, 0, stream>>>(
      (const __half2*)xw16, enbr, eoff, (__half2*)ef16, n_edges);
  node_agg128_kernel<<<(n_nodes * 64 + 255) / 256, 256, 0, stream>>>(
      (const __half2*)ef16, nnbr, noff, b1, (__half2*)h16, n_nodes);

  // layer 2
  gemm2_kernel<<<(n_nodes + 511) / 512, 256, 0, stream>>>(h16, W2, hw2, n_nodes);
  edge_agg16_kernel<<<(n_edges * 16 + 255) / 256, 256, 0, stream>>>(hw2, enbr, eoff, ef2, n_edges);
  node_agg16_kernel<<<(n_nodes * 16 + 255) / 256, 256, 0, stream>>>(ef2, nnbr, noff, b2, out, n_nodes);
}

// Round 8
// 424.272 us; speedup vs baseline: 2.7074x; 1.2149x over previous
//
#include <hip/hip_runtime.h>
#include <hip/hip_fp16.h>

// Problem constants: N_NODES=100000, N_EDGES=50000, NNZ=1600000, dims 128->128->16, fp32 I/O.
// Internal message path (xw, e_feat, h) stored fp16, accumulated fp32.
// CSR build: counting sort with NO global atomics anywhere (LDS histograms only).
// Agg kernels: 8-way unrolled gather loops for memory-level parallelism
// (index->gather addr dependency chain limits a 2-way loop to ~2 outstanding
//  gathers/wave; at ~500-900 cyc L3 latency that is the R7 96 us bottleneck).

#define N_EDGES_C 50000
#define F1 128
#define F2 16
#define CHUNK 4096                // elements per chunk (391 chunks -> good occupancy)
#define EBIN_SHIFT 7              // 128 edges per bin
#define NBIN_SHIFT 8              // 256 nodes per bin
#define EBINS 391                 // ceil(50000/128)
#define NBINS 391                 // ceil(100000/256)

// ---------------- CSR build ----------------

__global__ __launch_bounds__(256) void hist_chunk_kernel(
    const int* __restrict__ node_idx, const int* __restrict__ edge_idx,
    int* __restrict__ echunkcnt, int* __restrict__ nchunkcnt, int nnz) {
  __shared__ int ebc[EBINS], nbc[NBINS];
  const int t = threadIdx.x;
  for (int b = t; b < EBINS; b += 256) ebc[b] = 0;
  for (int b = t; b < NBINS; b += 256) nbc[b] = 0;
  __syncthreads();
  const int base = blockIdx.x * CHUNK;
  int end = base + CHUNK; if (end > nnz) end = nnz;
  for (int i = base + t; i < end; i += 256) {
    atomicAdd(&ebc[edge_idx[i] >> EBIN_SHIFT], 1);
    atomicAdd(&nbc[node_idx[i] >> NBIN_SHIFT], 1);
  }
  __syncthreads();
  const int nC = gridDim.x;
  for (int b = t; b < EBINS; b += 256) echunkcnt[b * nC + blockIdx.x] = ebc[b];
  for (int b = t; b < NBINS; b += 256) nchunkcnt[b * nC + blockIdx.x] = nbc[b];
}

// ---- runoff = exclusive prefix sum over flattened bin-major chunk counts ----

__global__ __launch_bounds__(256) void cscan_p1_kernel(
    const int* __restrict__ ecc, const int* __restrict__ ncc,
    int* __restrict__ epart, int* __restrict__ npart,
    int Le, int Ln, int nbE) {
  __shared__ int red[256];
  const int t = threadIdx.x;
  const int b = blockIdx.x;
  const int* src; int L; int* dst; int bb;
  if (b < nbE) { src = ecc; L = Le; dst = epart; bb = b; }
  else         { src = ncc; L = Ln; dst = npart; bb = b - nbE; }
  int base = bb * 1024 + t * 4;
  int s = 0;
#pragma unroll
  for (int j = 0; j < 4; ++j) { int i = base + j; if (i < L) s += src[i]; }
  red[t] = s;
  __syncthreads();
  for (int d = 128; d > 0; d >>= 1) {
    if (t < d) red[t] += red[t + d];
    __syncthreads();
  }
  if (t == 0) dst[bb] = red[0];
}

__global__ __launch_bounds__(256) void cscan_p2_kernel(
    int* __restrict__ epart, int* __restrict__ npart,
    int* __restrict__ ebinbase, int* __restrict__ nbinbase,
    int nbE, int nbN, int nnz) {
  __shared__ int se[256], sn[256];
  const int t = threadIdx.x;
  se[t] = (t < nbE) ? epart[t] : 0;
  sn[t] = (t < nbN) ? npart[t] : 0;
  __syncthreads();
  for (int d = 1; d < 256; d <<= 1) {
    int ve = (t >= d) ? se[t - d] : 0;
    int vn = (t >= d) ? sn[t - d] : 0;
    __syncthreads();
    se[t] += ve; sn[t] += vn;
    __syncthreads();
  }
  if (t < nbE) epart[t] = (t > 0) ? se[t - 1] : 0;
  if (t < nbN) npart[t] = (t > 0) ? sn[t - 1] : 0;
  if (t == 0) { ebinbase[EBINS] = nnz; nbinbase[NBINS] = nnz; }
}

__global__ __launch_bounds__(256) void cscan_p3_kernel(
    const int* __restrict__ ecc, const int* __restrict__ ncc,
    const int* __restrict__ epart, const int* __restrict__ npart,
    int* __restrict__ erunoff, int* __restrict__ nrunoff,
    int* __restrict__ ebinbase, int* __restrict__ nbinbase,
    int Le, int Ln, int nbE, int nC) {
  __shared__ int red[256];
  const int t = threadIdx.x;
  const int b = blockIdx.x;
  const int* src; const int* part; int L; int* ro; int* bba; int bb;
  if (b < nbE) { src = ecc; part = epart; L = Le; ro = erunoff; bba = ebinbase; bb = b; }
  else         { src = ncc; part = npart; L = Ln; ro = nrunoff; bba = nbinbase; bb = b - nbE; }
  int base = bb * 1024 + t * 4;
  int v[4]; int s = 0;
#pragma unroll
  for (int j = 0; j < 4; ++j) { int i = base + j; v[j] = (i < L) ? src[i] : 0; s += v[j]; }
  red[t] = s;
  __syncthreads();
  for (int d = 1; d < 256; d <<= 1) {
    int x = (t >= d) ? red[t - d] : 0;
    __syncthreads();
    red[t] += x;
    __syncthreads();
  }
  int run = part[bb] + ((t > 0) ? red[t - 1] : 0);
#pragma unroll
  for (int j = 0; j < 4; ++j) {
    int i = base + j;
    if (i < L) {
      ro[i] = run;
      if (i % nC == 0) bba[i / nC] = run;
      run += v[j];
    }
  }
}

// Stage pass: each chunk writes its pairs into contiguous per-(bin,chunk) runs.
__global__ __launch_bounds__(256) void stage_kernel(
    const int* __restrict__ node_idx, const int* __restrict__ edge_idx,
    const int* __restrict__ erunoff, const int* __restrict__ nrunoff,
    int2* __restrict__ epairs, int2* __restrict__ npairs, int nnz) {
  __shared__ int ecur[EBINS], ncur[NBINS];
  const int t = threadIdx.x;
  const int nC = gridDim.x;
  for (int b = t; b < EBINS; b += 256) ecur[b] = erunoff[b * nC + blockIdx.x];
  for (int b = t; b < NBINS; b += 256) ncur[b] = nrunoff[b * nC + blockIdx.x];
  __syncthreads();
  const int base = blockIdx.x * CHUNK;
  int end = base + CHUNK; if (end > nnz) end = nnz;
  for (int i = base + t; i < end; i += 256) {
    int e = edge_idx[i];
    int n = node_idx[i];
    int p = atomicAdd(&ecur[e >> EBIN_SHIFT], 1);
    epairs[p] = make_int2(e, n);
    int q = atomicAdd(&ncur[n >> NBIN_SHIFT], 1);
    npairs[q] = make_int2(n, e);
  }
}

// Final scatter: one block per bin. LDS histogram -> LDS exclusive scan gives
// per-segment CSR offsets (written to eoff/noff) AND scatter cursors.
__global__ __launch_bounds__(256) void bin_scatter_kernel(
    const int2* __restrict__ epairs, const int2* __restrict__ npairs,
    const int* __restrict__ ebinbase, const int* __restrict__ nbinbase,
    int* __restrict__ eoff, int* __restrict__ noff,
    int* __restrict__ enbr, int* __restrict__ nnbr,
    int n_edges, int n_nodes) {
  __shared__ int cnt[256];
  __shared__ int scn[256];
  const int bid = blockIdx.x;
  const int t = threadIdx.x;
  if (bid < EBINS) {
    const int e0 = bid << EBIN_SHIFT;
    const int ne = min(1 << EBIN_SHIFT, n_edges - e0);
    const int beg = ebinbase[bid], end = ebinbase[bid + 1];
    if (t < 128) cnt[t] = 0;
    __syncthreads();
    for (int j = beg + t; j < end; j += 256) atomicAdd(&cnt[epairs[j].x & 127], 1);
    __syncthreads();
    if (t < 128) scn[t] = cnt[t];
    __syncthreads();
    for (int d = 1; d < 128; d <<= 1) {
      int x = 0;
      if (t < 128 && t >= d) x = scn[t - d];
      __syncthreads();
      if (t < 128) scn[t] += x;
      __syncthreads();
    }
    int pos0 = 0;
    if (t < 128) {
      int excl = (t > 0) ? scn[t - 1] : 0;
      pos0 = beg + excl;
      if (t < ne) eoff[e0 + t] = pos0;
    }
    __syncthreads();
    if (t < 128) scn[t] = pos0;   // scatter cursors
    __syncthreads();
    for (int j = beg + t; j < end; j += 256) {
      int2 p = epairs[j];
      int pos = atomicAdd(&scn[p.x & 127], 1);
      enbr[pos] = p.y;
    }
    if (bid == EBINS - 1 && t == 0) eoff[n_edges] = end;
  } else {
    const int b = bid - EBINS;
    const int n0 = b << NBIN_SHIFT;
    const int nn = min(1 << NBIN_SHIFT, n_nodes - n0);
    const int beg = nbinbase[b], end = nbinbase[b + 1];
    cnt[t] = 0;
    __syncthreads();
    for (int j = beg + t; j < end; j += 256) atomicAdd(&cnt[npairs[j].x & 255], 1);
    __syncthreads();
    scn[t] = cnt[t];
    __syncthreads();
    for (int d = 1; d < 256; d <<= 1) {
      int x = (t >= d) ? scn[t - d] : 0;
      __syncthreads();
      scn[t] += x;
      __syncthreads();
    }
    int excl = (t > 0) ? scn[t - 1] : 0;
    int pos0 = beg + excl;
    if (t < nn) noff[n0 + t] = pos0;
    __syncthreads();
    scn[t] = pos0;
    __syncthreads();
    for (int j = beg + t; j < end; j += 256) {
      int2 p = npairs[j];
      int pos = atomicAdd(&scn[p.x & 255], 1);
      nnbr[pos] = p.y;
    }
    if (bid == EBINS + NBINS - 1 && t == 0) noff[n_nodes] = end;
  }
}

// ---------------- GEMM1: xw16[M x 128] = x[M x 128] @ W[128 x 128], fp16 out ----------------

__global__ __launch_bounds__(256) void gemm1_kernel(
    const float* __restrict__ A, const float* __restrict__ B,
    __half* __restrict__ C16, int M) {
  __shared__ float xs[128][36];
  __shared__ float wsh[32][128];

  const int t = threadIdx.x;
  const int tx = t & 15;
  const int ty = t >> 4;
  const int bm = blockIdx.x * 128;

  float acc[8][8];
#pragma unroll
  for (int i = 0; i < 8; ++i)
#pragma unroll
    for (int j = 0; j < 8; ++j) acc[i][j] = 0.f;

  for (int kt = 0; kt < 4; ++kt) {
#pragma unroll
    for (int i = 0; i < 4; ++i) {
      int lin = i * 256 + t;
      int row = lin >> 3;
      int c4 = lin & 7;
      int grow = bm + row;
      float4 v = make_float4(0.f, 0.f, 0.f, 0.f);
      if (grow < M) v = *(const float4*)(A + (size_t)grow * 128 + kt * 32 + c4 * 4);
      *(float4*)&xs[row][c4 * 4] = v;
    }
#pragma unroll
    for (int i = 0; i < 4; ++i) {
      int lin = i * 256 + t;
      int k = lin >> 5;
      int c4 = lin & 31;
      *(float4*)&wsh[k][c4 * 4] = *(const float4*)(B + (size_t)(kt * 32 + k) * 128 + c4 * 4);
    }
    __syncthreads();

#pragma unroll 4
    for (int k = 0; k < 32; ++k) {
      float a[8], b[8];
#pragma unroll
      for (int j = 0; j < 4; ++j) {
        a[j]     = xs[ty * 4 + j][k];
        a[4 + j] = xs[ty * 4 + 64 + j][k];
      }
      float4 b0 = *(const float4*)&wsh[k][tx * 4];
      float4 b1 = *(const float4*)&wsh[k][tx * 4 + 64];
      b[0] = b0.x; b[1] = b0.y; b[2] = b0.z; b[3] = b0.w;
      b[4] = b1.x; b[5] = b1.y; b[6] = b1.z; b[7] = b1.w;
#pragma unroll
      for (int i = 0; i < 8; ++i)
#pragma unroll
        for (int j = 0; j < 8; ++j) acc[i][j] = fmaf(a[i], b[j], acc[i][j]);
    }
    __syncthreads();
  }

#pragma unroll
  for (int i = 0; i < 8; ++i) {
    int row = (i < 4) ? (ty * 4 + i) : (ty * 4 + 64 + (i - 4));
    int grow = bm + row;
    if (grow < M) {
      __half2* rp = (__half2*)(C16 + (size_t)grow * 128);
      rp[tx * 2]      = __floats2half2_rn(acc[i][0], acc[i][1]);
      rp[tx * 2 + 1]  = __floats2half2_rn(acc[i][2], acc[i][3]);
      rp[32 + tx * 2]     = __floats2half2_rn(acc[i][4], acc[i][5]);
      rp[32 + tx * 2 + 1] = __floats2half2_rn(acc[i][6], acc[i][7]);
    }
  }
}

// ---------------- Segment aggregation, F=128 fp16 (one wave per segment) ----------------
// 8-way unrolled gather loop: 8 independent row-gathers in flight per wave.

__global__ __launch_bounds__(256) void edge_agg128_kernel(
    const __half2* __restrict__ feat, const int* __restrict__ nbr,
    const int* __restrict__ off, __half2* __restrict__ outf, int nseg) {
  int w = (blockIdx.x * 256 + threadIdx.x) >> 6;
  int lane = threadIdx.x & 63;
  if (w >= nseg) return;
  int beg = off[w], end = off[w + 1];
  float a0x = 0.f, a0y = 0.f, a1x = 0.f, a1y = 0.f;
  float a2x = 0.f, a2y = 0.f, a3x = 0.f, a3y = 0.f;
  int j = beg;
  for (; j + 8 <= end; j += 8) {
    int n0 = nbr[j],     n1 = nbr[j + 1], n2 = nbr[j + 2], n3 = nbr[j + 3];
    int n4 = nbr[j + 4], n5 = nbr[j + 5], n6 = nbr[j + 6], n7 = nbr[j + 7];
    float2 v0 = __half22float2(feat[(size_t)n0 * 64 + lane]);
    float2 v1 = __half22float2(feat[(size_t)n1 * 64 + lane]);
    float2 v2 = __half22float2(feat[(size_t)n2 * 64 + lane]);
    float2 v3 = __half22float2(feat[(size_t)n3 * 64 + lane]);
    float2 v4 = __half22float2(feat[(size_t)n4 * 64 + lane]);
    float2 v5 = __half22float2(feat[(size_t)n5 * 64 + lane]);
    float2 v6 = __half22float2(feat[(size_t)n6 * 64 + lane]);
    float2 v7 = __half22float2(feat[(size_t)n7 * 64 + lane]);
    a0x += v0.x + v4.x; a0y += v0.y + v4.y;
    a1x += v1.x + v5.x; a1y += v1.y + v5.y;
    a2x += v2.x + v6.x; a2y += v2.y + v6.y;
    a3x += v3.x + v7.x; a3y += v3.y + v7.y;
  }
  for (; j < end; ++j) {
    float2 v = __half22float2(feat[(size_t)nbr[j] * 64 + lane]);
    a0x += v.x; a0y += v.y;
  }
  float inv = (end > beg) ? 1.f / (float)(end - beg) : 0.f;
  float sx = (a0x + a1x) + (a2x + a3x);
  float sy = (a0y + a1y) + (a2y + a3y);
  outf[(size_t)w * 64 + lane] = __floats2half2_rn(sx * inv, sy * inv);
}

__global__ __launch_bounds__(256) void node_agg128_kernel(
    const __half2* __restrict__ feat, const int* __restrict__ nbr,
    const int* __restrict__ off, const float* __restrict__ bias,
    __half2* __restrict__ outf, int nseg) {
  int w = (blockIdx.x * 256 + threadIdx.x) >> 6;
  int lane = threadIdx.x & 63;
  if (w >= nseg) return;
  int beg = off[w], end = off[w + 1];
  float a0x = 0.f, a0y = 0.f, a1x = 0.f, a1y = 0.f;
  float a2x = 0.f, a2y = 0.f, a3x = 0.f, a3y = 0.f;
  int j = beg;
  for (; j + 8 <= end; j += 8) {
    int e0 = nbr[j],     e1 = nbr[j + 1], e2 = nbr[j + 2], e3 = nbr[j + 3];
    int e4 = nbr[j + 4], e5 = nbr[j + 5], e6 = nbr[j + 6], e7 = nbr[j + 7];
    float2 v0 = __half22float2(feat[(size_t)e0 * 64 + lane]);
    float2 v1 = __half22float2(feat[(size_t)e1 * 64 + lane]);
    float2 v2 = __half22float2(feat[(size_t)e2 * 64 + lane]);
    float2 v3 = __half22float2(feat[(size_t)e3 * 64 + lane]);
    float2 v4 = __half22float2(feat[(size_t)e4 * 64 + lane]);
    float2 v5 = __half22float2(feat[(size_t)e5 * 64 + lane]);
    float2 v6 = __half22float2(feat[(size_t)e6 * 64 + lane]);
    float2 v7 = __half22float2(feat[(size_t)e7 * 64 + lane]);
    a0x += v0.x + v4.x; a0y += v0.y + v4.y;
    a1x += v1.x + v5.x; a1y += v1.y + v5.y;
    a2x += v2.x + v6.x; a2y += v2.y + v6.y;
    a3x += v3.x + v7.x; a3y += v3.y + v7.y;
  }
  for (; j < end; ++j) {
    float2 v = __half22float2(feat[(size_t)nbr[j] * 64 + lane]);
    a0x += v.x; a0y += v.y;
  }
  float inv = (end > beg) ? 1.f / (float)(end - beg) : 0.f;
  float2 b = *(const float2*)(bias + lane * 2);
  float sx = (a0x + a1x) + (a2x + a3x);
  float sy = (a0y + a1y) + (a2y + a3y);
  float hx = fmaxf(sx * inv + b.x, 0.f);   // + b1, ReLU
  float hy = fmaxf(sy * inv + b.y, 0.f);
  outf[(size_t)w * 64 + lane] = __floats2half2_rn(hx, hy);
}

// ---------------- GEMM2: hw2[M x 16] = h16[M x 128] @ W2[128 x 16] ----------------

__global__ __launch_bounds__(256) void gemm2_kernel(
    const __half* __restrict__ H16, const float* __restrict__ W2,
    float* __restrict__ O, int M) {
  __shared__ float ws2[128 * 16];
  const int t = threadIdx.x;
#pragma unroll
  for (int i = 0; i < 8; ++i) ws2[i * 256 + t] = W2[i * 256 + t];
  __syncthreads();

  int r0 = blockIdx.x * 512 + t;
  int r1 = r0 + 256;
  bool v0 = r0 < M, v1 = r1 < M;
  const __half2* h0 = (const __half2*)(H16 + (size_t)r0 * 128);
  const __half2* h1 = (const __half2*)(H16 + (size_t)r1 * 128);

  float4 acc0[4], acc1[4];
#pragma unroll
  for (int q = 0; q < 4; ++q) {
    acc0[q] = make_float4(0.f, 0.f, 0.f, 0.f);
    acc1[q] = make_float4(0.f, 0.f, 0.f, 0.f);
  }

  for (int k4 = 0; k4 < 32; ++k4) {
    float2 f00 = make_float2(0.f, 0.f), f01 = make_float2(0.f, 0.f);
    float2 f10 = make_float2(0.f, 0.f), f11 = make_float2(0.f, 0.f);
    if (v0) { f00 = __half22float2(h0[2 * k4]); f01 = __half22float2(h0[2 * k4 + 1]); }
    if (v1) { f10 = __half22float2(h1[2 * k4]); f11 = __half22float2(h1[2 * k4 + 1]); }
    const float a0s[4] = {f00.x, f00.y, f01.x, f01.y};
    const float a1s[4] = {f10.x, f10.y, f11.x, f11.y};
#pragma unroll
    for (int j = 0; j < 4; ++j) {
      int k = k4 * 4 + j;
#pragma unroll
      for (int q = 0; q < 4; ++q) {
        float4 b = *(const float4*)&ws2[k * 16 + q * 4];
        acc0[q].x = fmaf(a0s[j], b.x, acc0[q].x);
        acc0[q].y = fmaf(a0s[j], b.y, acc0[q].y);
        acc0[q].z = fmaf(a0s[j], b.z, acc0[q].z);
        acc0[q].w = fmaf(a0s[j], b.w, acc0[q].w);
        acc1[q].x = fmaf(a1s[j], b.x, acc1[q].x);
        acc1[q].y = fmaf(a1s[j], b.y, acc1[q].y);
        acc1[q].z = fmaf(a1s[j], b.z, acc1[q].z);
        acc1[q].w = fmaf(a1s[j], b.w, acc1[q].w);
      }
    }
  }
  if (v0) {
#pragma unroll
    for (int q = 0; q < 4; ++q) *(float4*)(O + (size_t)r0 * 16 + q * 4) = acc0[q];
  }
  if (v1) {
#pragma unroll
    for (int q = 0; q < 4; ++q) *(float4*)(O + (size_t)r1 * 16 + q * 4) = acc1[q];
  }
}

// ---------------- Segment aggregation, F=16 (fp32), 8-way unrolled ----------------

__global__ __launch_bounds__(256) void edge_agg16_kernel(
    const float* __restrict__ feat, const int* __restrict__ nbr,
    const int* __restrict__ off, float* __restrict__ outf, int nseg) {
  int gid = blockIdx.x * 256 + threadIdx.x;
  int seg = gid >> 4;
  int c = gid & 15;
  if (seg >= nseg) return;
  int beg = off[seg], end = off[seg + 1];
  float a0 = 0.f, a1 = 0.f, a2 = 0.f, a3 = 0.f;
  int j = beg;
  for (; j + 8 <= end; j += 8) {
    int n0 = nbr[j],     n1 = nbr[j + 1], n2 = nbr[j + 2], n3 = nbr[j + 3];
    int n4 = nbr[j + 4], n5 = nbr[j + 5], n6 = nbr[j + 6], n7 = nbr[j + 7];
    float v0 = feat[(size_t)n0 * 16 + c];
    float v1 = feat[(size_t)n1 * 16 + c];
    float v2 = feat[(size_t)n2 * 16 + c];
    float v3 = feat[(size_t)n3 * 16 + c];
    float v4 = feat[(size_t)n4 * 16 + c];
    float v5 = feat[(size_t)n5 * 16 + c];
    float v6 = feat[(size_t)n6 * 16 + c];
    float v7 = feat[(size_t)n7 * 16 + c];
    a0 += v0 + v4; a1 += v1 + v5; a2 += v2 + v6; a3 += v3 + v7;
  }
  for (; j < end; ++j) a0 += feat[(size_t)nbr[j] * 16 + c];
  float inv = (end > beg) ? 1.f / (float)(end - beg) : 0.f;
  outf[(size_t)seg * 16 + c] = ((a0 + a1) + (a2 + a3)) * inv;
}

__global__ __launch_bounds__(256) void node_agg16_kernel(
    const float* __restrict__ feat, const int* __restrict__ nbr,
    const int* __restrict__ off, const float* __restrict__ bias,
    float* __restrict__ outf, int nseg) {
  int gid = blockIdx.x * 256 + threadIdx.x;
  int seg = gid >> 4;
  int c = gid & 15;
  if (seg >= nseg) return;
  int beg = off[seg], end = off[seg + 1];
  float a0 = 0.f, a1 = 0.f, a2 = 0.f, a3 = 0.f;
  int j = beg;
  for (; j + 8 <= end; j += 8) {
    int n0 = nbr[j],     n1 = nbr[j + 1], n2 = nbr[j + 2], n3 = nbr[j + 3];
    int n4 = nbr[j + 4], n5 = nbr[j + 5], n6 = nbr[j + 6], n7 = nbr[j + 7];
    float v0 = feat[(size_t)n0 * 16 + c];
    float v1 = feat[(size_t)n1 * 16 + c];
    float v2 = feat[(size_t)n2 * 16 + c];
    float v3 = feat[(size_t)n3 * 16 + c];
    float v4 = feat[(size_t)n4 * 16 + c];
    float v5 = feat[(size_t)n5 * 16 + c];
    float v6 = feat[(size_t)n6 * 16 + c];
    float v7 = feat[(size_t)n7 * 16 + c];
    a0 += v0 + v4; a1 += v1 + v5; a2 += v2 + v6; a3 += v3 + v7;
  }
  for (; j < end; ++j) a0 += feat[(size_t)nbr[j] * 16 + c];
  float inv = (end > beg) ? 1.f / (float)(end - beg) : 0.f;
  outf[(size_t)seg * 16 + c] = ((a0 + a1) + (a2 + a3)) * inv + bias[c];
}

// ---------------- launch ----------------

extern "C" void kernel_launch(void* const* d_in, const int* in_sizes, int n_in,
                              void* d_out, int out_size, void* d_ws, size_t ws_size,
                              hipStream_t stream) {
  const float* x        = (const float*)d_in[0];
  const int*   node_idx = (const int*)d_in[1];
  const int*   edge_idx = (const int*)d_in[2];
  const float* W1 = (const float*)d_in[4];
  const float* b1 = (const float*)d_in[5];
  const float* W2 = (const float*)d_in[6];
  const float* b2 = (const float*)d_in[7];
  float* out = (float*)d_out;

  const int n_nodes = in_sizes[0] / F1;  // 100000
  const int nnz     = in_sizes[1];       // 1600000
  const int n_edges = N_EDGES_C;         // 50000
  const int nC      = (nnz + CHUNK - 1) / CHUNK;   // 391
  const int Le      = EBINS * nC;                  // 152,881
  const int Ln      = NBINS * nC;
  const int nbE     = (Le + 1023) / 1024;          // 150
  const int nbN     = (Ln + 1023) / 1024;

  char* ws = (char*)d_ws;
  // layout (bytes), high-water ~89.5 MB (97.4 MB known-safe from R1):
  int2*   epairs = (int2*)(ws + 0);            // 12.8M transient (consumed by bin_scatter)
  int2*   npairs = (int2*)(ws + 12800000);     // 12.8M transient
  __half* h16    = (__half*)(ws + 0);          // 25.6M (written by nagg128, after bin_scatter)
  __half* xw16   = (__half*)(ws + 25600000);   // 25.6M
  __half* ef16   = (__half*)(ws + 51200000);   // 12.8M
  float*  hw2    = (float*)(ws + 64000000);    //  6.4M
  float*  ef2    = (float*)(ws + 70400000);    //  3.2M
  int*    enbr   = (int*)(ws + 73600000);      //  6.4M
  int*    nnbr   = (int*)(ws + 80000000);      //  6.4M
  int*    eoff   = (int*)(ws + 86400000);      //  200,004
  int*    noff   = (int*)(ws + 86600008);      //  400,004
  int*    echunkcnt = (int*)(ws + 87000016);   //  611,524 (EBINS*nC)
  int*    nchunkcnt = (int*)(ws + 87611540);   //  611,524
  int*    erunoff   = (int*)(ws + 88223064);   //  611,524
  int*    nrunoff   = (int*)(ws + 88834588);   //  611,524
  int*    ebinbase  = (int*)(ws + 89446112);   //  1,568 (392 ints)
  int*    nbinbase  = (int*)(ws + 89447680);   //  1,568
  int*    epart     = (int*)(ws + 89449248);   //  1,024 (256 ints)
  int*    npart     = (int*)(ws + 89450272);   //  1,024 -> end 89,451,296

  hist_chunk_kernel<<<nC, 256, 0, stream>>>(node_idx, edge_idx,
                                            echunkcnt, nchunkcnt, nnz);
  cscan_p1_kernel<<<nbE + nbN, 256, 0, stream>>>(echunkcnt, nchunkcnt,
                                                 epart, npart, Le, Ln, nbE);
  cscan_p2_kernel<<<1, 256, 0, stream>>>(epart, npart, ebinbase, nbinbase,
                                         nbE, nbN, nnz);
  cscan_p3_kernel<<<nbE + nbN, 256, 0, stream>>>(echunkcnt, nchunkcnt,
                                                 epart, npart, erunoff, nrunoff,
                                                 ebinbase, nbinbase, Le, Ln, nbE, nC);
  stage_kernel<<<nC, 256, 0, stream>>>(node_idx, edge_idx, erunoff, nrunoff,
                                       epairs, npairs, nnz);
  bin_scatter_kernel<<<EBINS + NBINS, 256, 0, stream>>>(epairs, npairs,
                                                        ebinbase, nbinbase,
                                                        eoff, noff, enbr, nnbr,
                                                        n_edges, n_nodes);

  // layer 1 (fp16 message path)
  gemm1_kernel<<<(n_nodes + 127) / 128, 256, 0, stream>>>(x, W1, xw16, n_nodes);
  edge_agg128_kernel<<<(n_edges * 64 + 255) / 256, 256, 0, stream>>>(
      (const __half2*)xw16, enbr, eoff, (__half2*)ef16, n_edges);
  node_agg128_kernel<<<(n_nodes * 64 + 255) / 256, 256, 0, stream>>>(
      (const __half2*)ef16, nnbr, noff, b1, (__half2*)h16, n_nodes);

  // layer 2
  gemm2_kernel<<<(n_nodes + 511) / 512, 256, 0, stream>>>(h16, W2, hw2, n_nodes);
  edge_agg16_kernel<<<(n_edges * 16 + 255) / 256, 256, 0, stream>>>(hw2, enbr, eoff, ef2, n_edges);
  node_agg16_kernel<<<(n_nodes * 16 + 255) / 256, 256, 0, stream>>>(ef2, nnbr, noff, b2, out, n_nodes);
}